// Round 1
// baseline (527.318 us; speedup 1.0000x reference)
//
#include <hip/hip_runtime.h>
#include <stdint.h>

// Round 0: full bf16-MFMA pipeline for the single-head transformer block.
// Structure: cast/transpose -> QKV gemms -> S=QK^T (causal lower blocks) ->
// in-place causal softmax (fp32 S -> bf16 A) -> O=A@V (k-limited) ->
// add+LayerNorm -> FFN1(relu) -> FFN2.
// GEMM is the m97-style 128x128 tile, BK=32, global_load_lds width=16,
// v_mfma_f32_16x16x32_bf16, 4 waves x 4x4 accumulators.
// Workspace requirement: 166 MB.

using short8 = __attribute__((ext_vector_type(8))) short;
using f32x4  = __attribute__((ext_vector_type(4))) float;

__device__ __forceinline__ uint16_t f2bf(float f) {
  uint32_t u = __builtin_bit_cast(uint32_t, f);
  u += 0x7FFFu + ((u >> 16) & 1u);        // RNE, inputs are finite
  return (uint16_t)(u >> 16);
}

__device__ __forceinline__ void gload_lds16(const uint16_t* g, uint16_t* l) {
  __builtin_amdgcn_global_load_lds(
      (__attribute__((address_space(1))) void*)(void*)g,
      (__attribute__((address_space(3))) void*)l, 16, 0, 0);
}

// ---------------- GEMM: C[M,N] = scale * A[M,K] @ Bt[N,K]^T + bias ----------
// mode 0: full grid.  mode 1: causal-S, skip blocks strictly above diagonal.
// mode 2: causal-O, K limited to (bm+1)*128 per block row.
__global__ __launch_bounds__(256) void gemm_bt(
    const uint16_t* __restrict__ A, const uint16_t* __restrict__ Bt,
    const float* __restrict__ bias, void* __restrict__ Cout,
    int M, int N, int K, int lda, int ldb, int ldc,
    float scale, int out_bf16, int relu, int mode)
{
  constexpr int BK = 32;
  __shared__ uint16_t As[128 * BK];
  __shared__ uint16_t Bs[128 * BK];
  int bm = blockIdx.y, bn = blockIdx.x;
  if (mode == 1 && bn > bm) return;                // fully-masked causal block
  int kmax = (mode == 2) ? ((bm + 1) << 7) : K;
  if (kmax > K) kmax = K;

  int tid  = threadIdx.x;
  int lane = tid & 63;
  int wave = tid >> 6;
  int wm = (wave >> 1) * 64, wn = (wave & 1) * 64; // wave's 64x64 quadrant
  int lr = lane & 15, quad = lane >> 4;

  // staging: 512 16B-chunks per tile (128 rows x 4 chunks), 2 per thread each
  int c0 = tid, c1 = tid + 256;
  const uint16_t* Ag0 = A  + (size_t)(bm * 128 + (c0 >> 2)) * lda + (c0 & 3) * 8;
  const uint16_t* Ag1 = A  + (size_t)(bm * 128 + (c1 >> 2)) * lda + (c1 & 3) * 8;
  const uint16_t* Bg0 = Bt + (size_t)(bn * 128 + (c0 >> 2)) * ldb + (c0 & 3) * 8;
  const uint16_t* Bg1 = Bt + (size_t)(bn * 128 + (c1 >> 2)) * ldb + (c1 & 3) * 8;
  uint16_t* Al0 = As + c0 * 8; uint16_t* Al1 = As + c1 * 8;
  uint16_t* Bl0 = Bs + c0 * 8; uint16_t* Bl1 = Bs + c1 * 8;

  f32x4 acc[4][4] = {};

  for (int k0 = 0; k0 < kmax; k0 += BK) {
    __syncthreads();                                // LDS free before overwrite
    gload_lds16(Ag0 + k0, Al0);
    gload_lds16(Ag1 + k0, Al1);
    gload_lds16(Bg0 + k0, Bl0);
    gload_lds16(Bg1 + k0, Bl1);
    __syncthreads();                                // drains vmcnt (compiler)
    short8 af[4], bfr[4];
#pragma unroll
    for (int i = 0; i < 4; ++i)
      af[i] = *(const short8*)(&As[(wm + i * 16 + lr) * BK + quad * 8]);
#pragma unroll
    for (int j = 0; j < 4; ++j)
      bfr[j] = *(const short8*)(&Bs[(wn + j * 16 + lr) * BK + quad * 8]);
#pragma unroll
    for (int i = 0; i < 4; ++i)
#pragma unroll
      for (int j = 0; j < 4; ++j)
        acc[i][j] = __builtin_amdgcn_mfma_f32_16x16x32_bf16(af[i], bfr[j], acc[i][j], 0, 0, 0);
  }

  // epilogue: C/D layout col=lane&15, row=quad*4+reg  [m89/m91 verified]
  int row0 = bm * 128 + wm + quad * 4;
  int col0 = bn * 128 + wn + lr;
#pragma unroll
  for (int j = 0; j < 4; ++j) {
    int col = col0 + j * 16;
    float bv = bias ? bias[col] : 0.0f;
#pragma unroll
    for (int i = 0; i < 4; ++i) {
#pragma unroll
      for (int r = 0; r < 4; ++r) {
        int row = row0 + i * 16 + r;
        float v = acc[i][j][r] * scale + bv;
        if (relu) v = fmaxf(v, 0.0f);
        size_t idx = (size_t)row * ldc + col;
        if (out_bf16) ((uint16_t*)Cout)[idx] = f2bf(v);
        else          ((float*)Cout)[idx]    = v;
      }
    }
  }
}

// ---------------- reductions ------------------------------------------------
__device__ __forceinline__ float block_sum(float v, float* red) {
#pragma unroll
  for (int o = 32; o > 0; o >>= 1) v += __shfl_xor(v, o, 64);
  if ((threadIdx.x & 63) == 0) red[threadIdx.x >> 6] = v;
  __syncthreads();
  v = red[0] + red[1] + red[2] + red[3];
  __syncthreads();
  return v;
}
__device__ __forceinline__ float block_max(float v, float* red) {
#pragma unroll
  for (int o = 32; o > 0; o >>= 1) v = fmaxf(v, __shfl_xor(v, o, 64));
  if ((threadIdx.x & 63) == 0) red[threadIdx.x >> 6] = v;
  __syncthreads();
  v = fmaxf(fmaxf(red[0], red[1]), fmaxf(red[2], red[3]));
  __syncthreads();
  return v;
}

// ---------------- causal softmax, in-place fp32 S -> bf16 A -----------------
// Row i valid for j<=i; writes zeros up to the 128-block boundary so the
// O-gemm (k < (bm+1)*128) never reads undefined bytes. All S reads are staged
// to registers before the first write (in-place is safe: one block per row).
__global__ __launch_bounds__(256) void softmax_causal(float* __restrict__ S) {
  __shared__ float red[4];
  int i = blockIdx.x, tid = threadIdx.x;
  float* srow = S + (size_t)i * 4096;
  uint16_t* arow = (uint16_t*)srow;
  int lim = ((i >> 7) + 1) << 7;
  float v[16];
  float mx = -3.4e38f;
#pragma unroll
  for (int it = 0; it < 16; ++it) {
    int j = it * 256 + tid;
    float x = -3.4e38f;
    if (j <= i) x = srow[j];
    v[it] = x;
    mx = fmaxf(mx, x);
  }
  mx = block_max(mx, red);                 // barrier: all reads complete here
  float sum = 0.0f;
#pragma unroll
  for (int it = 0; it < 16; ++it) {
    float e = __expf(v[it] - mx);          // masked lanes underflow to 0
    v[it] = e;
    sum += e;
  }
  sum = block_sum(sum, red);
  float inv = 1.0f / sum;
#pragma unroll
  for (int it = 0; it < 16; ++it) {
    int j = it * 256 + tid;
    if (j < lim) arow[j] = f2bf(v[it] * inv);
  }
}

// ---------------- residual add + LayerNorm -> bf16 --------------------------
__global__ __launch_bounds__(256) void add_layernorm(
    const float* __restrict__ O, const float* __restrict__ emb,
    const float* __restrict__ gamma, const float* __restrict__ beta,
    uint16_t* __restrict__ xB)
{
  __shared__ float red[4];
  int i = blockIdx.x, tid = threadIdx.x;
  float4 a = ((const float4*)(O   + (size_t)i * 1024))[tid];
  float4 b = ((const float4*)(emb + (size_t)i * 1024))[tid];
  float x0 = a.x + b.x, x1 = a.y + b.y, x2 = a.z + b.z, x3 = a.w + b.w;
  float mu = block_sum(x0 + x1 + x2 + x3, red) * (1.0f / 1024.0f);
  float d0 = x0 - mu, d1 = x1 - mu, d2 = x2 - mu, d3 = x3 - mu;
  float var = block_sum(d0 * d0 + d1 * d1 + d2 * d2 + d3 * d3, red) * (1.0f / 1024.0f);
  float rs = rsqrtf(var + 1e-5f);
  float4 g  = ((const float4*)gamma)[tid];
  float4 be = ((const float4*)beta)[tid];
  ushort4 o;
  o.x = f2bf(d0 * rs * g.x + be.x);
  o.y = f2bf(d1 * rs * g.y + be.y);
  o.z = f2bf(d2 * rs * g.z + be.z);
  o.w = f2bf(d3 * rs * g.w + be.w);
  ((ushort4*)(xB + (size_t)i * 1024))[tid] = o;
}

// ---------------- casts / transposes ----------------------------------------
__global__ __launch_bounds__(256) void cast_f32_bf16(
    const float* __restrict__ in, uint16_t* __restrict__ out, int n4)
{
  int idx = blockIdx.x * 256 + threadIdx.x;
  if (idx >= n4) return;
  float4 v = ((const float4*)in)[idx];
  ushort4 o; o.x = f2bf(v.x); o.y = f2bf(v.y); o.z = f2bf(v.z); o.w = f2bf(v.w);
  ((ushort4*)out)[idx] = o;
}

// fp32 [R,C] -> bf16 [C,R]
__global__ __launch_bounds__(256) void cast_transpose(
    const float* __restrict__ in, uint16_t* __restrict__ out, int R, int C)
{
  __shared__ float tile[32][33];
  int tx = threadIdx.x & 31, ty = threadIdx.x >> 5;
  int r0 = blockIdx.y * 32, c0 = blockIdx.x * 32;
#pragma unroll
  for (int r = 0; r < 32; r += 8)
    tile[ty + r][tx] = in[(size_t)(r0 + ty + r) * C + c0 + tx];
  __syncthreads();
#pragma unroll
  for (int r = 0; r < 32; r += 8)
    out[(size_t)(c0 + ty + r) * R + r0 + tx] = f2bf(tile[tx][ty + r]);
}

// bf16 [R,C] -> bf16 [C,R]
__global__ __launch_bounds__(256) void transpose_u16(
    const uint16_t* __restrict__ in, uint16_t* __restrict__ out, int R, int C)
{
  __shared__ uint16_t tile[32][33];
  int tx = threadIdx.x & 31, ty = threadIdx.x >> 5;
  int r0 = blockIdx.y * 32, c0 = blockIdx.x * 32;
#pragma unroll
  for (int r = 0; r < 32; r += 8)
    tile[ty + r][tx] = in[(size_t)(r0 + ty + r) * C + c0 + tx];
  __syncthreads();
#pragma unroll
  for (int r = 0; r < 32; r += 8)
    out[(size_t)(c0 + ty + r) * R + r0 + tx] = tile[tx][ty + r];
}

// ---------------- launcher --------------------------------------------------
extern "C" void kernel_launch(void* const* d_in, const int* in_sizes, int n_in,
                              void* d_out, int out_size, void* d_ws, size_t ws_size,
                              hipStream_t stream) {
  const float* emb   = (const float*)d_in[0];
  const float* Wq    = (const float*)d_in[1];
  const float* bq    = (const float*)d_in[2];
  const float* Wk    = (const float*)d_in[3];
  const float* bk    = (const float*)d_in[4];
  const float* Wv    = (const float*)d_in[5];
  const float* bv    = (const float*)d_in[6];
  const float* gamma = (const float*)d_in[7];
  const float* beta  = (const float*)d_in[8];
  const float* W1    = (const float*)d_in[9];
  const float* b1    = (const float*)d_in[10];
  const float* W2    = (const float*)d_in[11];
  const float* b2    = (const float*)d_in[12];

  char* w = (char*)d_ws;
  const size_t MB = 1ull << 20;
  uint16_t* embB = (uint16_t*)(w + 0 * MB);    // [4096,1024] bf16
  uint16_t* WqT  = (uint16_t*)(w + 8 * MB);    // [1024,1024] (N,K)
  uint16_t* WkT  = (uint16_t*)(w + 10 * MB);
  uint16_t* WvT  = (uint16_t*)(w + 12 * MB);
  uint16_t* W1T  = (uint16_t*)(w + 14 * MB);   // [4096,1024]
  uint16_t* W2T  = (uint16_t*)(w + 22 * MB);   // [1024,4096]
  uint16_t* Qb   = (uint16_t*)(w + 30 * MB);   // [4096,1024]
  uint16_t* Kb   = (uint16_t*)(w + 38 * MB);
  uint16_t* Vb   = (uint16_t*)(w + 46 * MB);
  uint16_t* Vt   = (uint16_t*)(w + 54 * MB);   // [1024,4096]
  uint16_t* xB   = (uint16_t*)(w + 62 * MB);   // [4096,1024]
  uint16_t* hB   = (uint16_t*)(w + 70 * MB);   // [4096,4096]
  float*    S    = (float*)(w + 102 * MB);     // [4096,4096] fp32; A bf16 in-place
  // total ws requirement: 166 MB

  // precision prep (every call: ws is re-poisoned, no caching allowed)
  cast_f32_bf16 <<<4096, 256, 0, stream>>>(emb, embB, 1024 * 1024);
  cast_transpose<<<dim3(32, 32),  256, 0, stream>>>(Wq, WqT, 1024, 1024);
  cast_transpose<<<dim3(32, 32),  256, 0, stream>>>(Wk, WkT, 1024, 1024);
  cast_transpose<<<dim3(32, 32),  256, 0, stream>>>(Wv, WvT, 1024, 1024);
  cast_transpose<<<dim3(128, 32), 256, 0, stream>>>(W1, W1T, 1024, 4096);
  cast_transpose<<<dim3(32, 128), 256, 0, stream>>>(W2, W2T, 4096, 1024);

  // QKV
  gemm_bt<<<dim3(8, 32), 256, 0, stream>>>(embB, WqT, bq, Qb, 4096, 1024, 1024, 1024, 1024, 1024, 1.0f, 1, 0, 0);
  gemm_bt<<<dim3(8, 32), 256, 0, stream>>>(embB, WkT, bk, Kb, 4096, 1024, 1024, 1024, 1024, 1024, 1.0f, 1, 0, 0);
  gemm_bt<<<dim3(8, 32), 256, 0, stream>>>(embB, WvT, bv, Vb, 4096, 1024, 1024, 1024, 1024, 1024, 1.0f, 1, 0, 0);
  transpose_u16<<<dim3(32, 128), 256, 0, stream>>>(Vb, Vt, 4096, 1024);

  // attention: S (causal lower blocks) -> softmax (in-place bf16) -> O into d_out
  gemm_bt<<<dim3(32, 32), 256, 0, stream>>>(Qb, Kb, nullptr, S, 4096, 4096, 1024, 1024, 1024, 4096, 0.03125f, 0, 0, 1);
  softmax_causal<<<4096, 256, 0, stream>>>(S);
  gemm_bt<<<dim3(8, 32), 256, 0, stream>>>((uint16_t*)S, Vt, nullptr, d_out, 4096, 1024, 4096, 8192, 4096, 1024, 1.0f, 0, 0, 2);

  // add+LN -> FFN
  add_layernorm<<<4096, 256, 0, stream>>>((const float*)d_out, emb, gamma, beta, xB);
  gemm_bt<<<dim3(32, 32), 256, 0, stream>>>(xB, W1T, b1, hB, 4096, 4096, 1024, 1024, 1024, 4096, 1.0f, 1, 1, 0);
  gemm_bt<<<dim3(8, 32), 256, 0, stream>>>(hB, W2T, b2, (float*)d_out, 4096, 1024, 4096, 4096, 4096, 1024, 1.0f, 0, 0, 0);
}

// Round 2
// 473.255 us; speedup vs baseline: 1.1142x; 1.1142x over previous
//
#include <hip/hip_runtime.h>
#include <stdint.h>

// Round 2: QKV fused into one 768-block gemm (3 blocks/CU); BLOCK_N=64 gemm
// variant for the N=1024 gemms (O, FFN2) -> 512 blocks; XOR-swizzled LDS
// (conflict-free ds_read_b128); triangular 528-block launch for causal S.
// Workspace requirement: 159 MB.

using short8 = __attribute__((ext_vector_type(8))) short;
using f32x4  = __attribute__((ext_vector_type(4))) float;

__device__ __forceinline__ uint16_t f2bf(float f) {
  uint32_t u = __builtin_bit_cast(uint32_t, f);
  u += 0x7FFFu + ((u >> 16) & 1u);        // RNE, inputs are finite
  return (uint16_t)(u >> 16);
}

__device__ __forceinline__ void gload_lds16(const uint16_t* g, uint16_t* l) {
  __builtin_amdgcn_global_load_lds(
      (__attribute__((address_space(1))) void*)(void*)g,
      (__attribute__((address_space(3))) void*)l, 16, 0, 0);
}

// LDS swizzle: slot s (16B chunks) holds global chunk-col (s&3)^((s>>3)&3) of
// row s>>2. Read of (row r, chunk q) -> slot r*4 + (q ^ ((r>>1)&3)).
// Per-SIMD32-phase banks spread uniformly (4 deep) -> conflict-free.

// ---------------- GEMM 128x128: C = scale*A@Bt^T + bias ---------------------
// mode 0: 2-D grid. mode 1: triangular causal-S launch, 1-D grid of 528.
__global__ __launch_bounds__(256) void gemm_bt(
    const uint16_t* __restrict__ A, const uint16_t* __restrict__ Bt,
    const float* __restrict__ bias, void* __restrict__ Cout,
    int K, int lda, int ldb, int ldc,
    float scale, int out_bf16, int relu, int mode)
{
  constexpr int BK = 32;
  __shared__ uint16_t As[128 * BK];
  __shared__ uint16_t Bs[128 * BK];
  int bm, bn;
  if (mode == 1) {                         // decode t -> lower-triangle (bm,bn)
    int t = blockIdx.x;
    bm = (int)((sqrtf(8.0f * (float)t + 1.0f) - 1.0f) * 0.5f);
    while ((bm + 1) * (bm + 2) / 2 <= t) ++bm;
    while (bm * (bm + 1) / 2 > t) --bm;
    bn = t - bm * (bm + 1) / 2;
  } else {
    bm = blockIdx.y; bn = blockIdx.x;
  }

  int tid  = threadIdx.x;
  int lane = tid & 63;
  int wave = tid >> 6;
  int wm = (wave >> 1) * 64, wn = (wave & 1) * 64;
  int lr = lane & 15, quad = lane >> 4;

  // staging with source-side swizzle (dest lane->slot mapping is fixed HW)
  int c0 = tid, c1 = tid + 256;
  int ra0 = c0 >> 2, qa0 = (c0 & 3) ^ ((c0 >> 3) & 3);
  int ra1 = c1 >> 2, qa1 = (c1 & 3) ^ ((c1 >> 3) & 3);
  const uint16_t* Ag0 = A  + (size_t)(bm * 128 + ra0) * lda + qa0 * 8;
  const uint16_t* Ag1 = A  + (size_t)(bm * 128 + ra1) * lda + qa1 * 8;
  const uint16_t* Bg0 = Bt + (size_t)(bn * 128 + ra0) * ldb + qa0 * 8;
  const uint16_t* Bg1 = Bt + (size_t)(bn * 128 + ra1) * ldb + qa1 * 8;
  uint16_t* Al0 = As + c0 * 8; uint16_t* Al1 = As + c1 * 8;
  uint16_t* Bl0 = Bs + c0 * 8; uint16_t* Bl1 = Bs + c1 * 8;

  f32x4 acc[4][4] = {};

  for (int k0 = 0; k0 < K; k0 += BK) {
    __syncthreads();
    gload_lds16(Ag0 + k0, Al0);
    gload_lds16(Ag1 + k0, Al1);
    gload_lds16(Bg0 + k0, Bl0);
    gload_lds16(Bg1 + k0, Bl1);
    __syncthreads();
    short8 af[4], bfr[4];
#pragma unroll
    for (int i = 0; i < 4; ++i) {
      int r = wm + i * 16 + lr;
      af[i] = *(const short8*)(&As[(r * 4 + (quad ^ ((r >> 1) & 3))) * 8]);
    }
#pragma unroll
    for (int j = 0; j < 4; ++j) {
      int r = wn + j * 16 + lr;
      bfr[j] = *(const short8*)(&Bs[(r * 4 + (quad ^ ((r >> 1) & 3))) * 8]);
    }
#pragma unroll
    for (int i = 0; i < 4; ++i)
#pragma unroll
      for (int j = 0; j < 4; ++j)
        acc[i][j] = __builtin_amdgcn_mfma_f32_16x16x32_bf16(af[i], bfr[j], acc[i][j], 0, 0, 0);
  }

  int row0 = bm * 128 + wm + quad * 4;
  int col0 = bn * 128 + wn + lr;
#pragma unroll
  for (int j = 0; j < 4; ++j) {
    int col = col0 + j * 16;
    float bv = bias ? bias[col] : 0.0f;
#pragma unroll
    for (int i = 0; i < 4; ++i) {
#pragma unroll
      for (int r = 0; r < 4; ++r) {
        int row = row0 + i * 16 + r;
        float v = acc[i][j][r] * scale + bv;
        if (relu) v = fmaxf(v, 0.0f);
        size_t idx = (size_t)row * ldc + col;
        if (out_bf16) ((uint16_t*)Cout)[idx] = f2bf(v);
        else          ((float*)Cout)[idx]    = v;
      }
    }
  }
}

// ---------------- GEMM 128x64 (for N=1024 outputs; 512-block grids) ---------
// mode 2: causal-O, K limited to (bm+1)*128; bm remapped for load balance.
__global__ __launch_bounds__(256) void gemm_bt_n64(
    const uint16_t* __restrict__ A, const uint16_t* __restrict__ Bt,
    const float* __restrict__ bias, void* __restrict__ Cout,
    int K, int lda, int ldb, int ldc,
    float scale, int out_bf16, int relu, int mode)
{
  constexpr int BK = 32;
  __shared__ uint16_t As[128 * BK];
  __shared__ uint16_t Bs[64 * BK];
  int bn = blockIdx.x;
  int b  = blockIdx.y;
  int bm = (mode == 2) ? ((b & 1) ? (31 - (b >> 1)) : (b >> 1)) : b;
  int kmax = (mode == 2) ? ((bm + 1) << 7) : K;
  if (kmax > K) kmax = K;

  int tid  = threadIdx.x;
  int lane = tid & 63;
  int wave = tid >> 6;
  int wm = (wave & 1) * 64, wn = (wave >> 1) * 32;   // wave: 64 rows x 32 cols
  int lr = lane & 15, quad = lane >> 4;

  int c0 = tid, c1 = tid + 256;                       // A: 512 chunks
  int ra0 = c0 >> 2, qa0 = (c0 & 3) ^ ((c0 >> 3) & 3);
  int ra1 = c1 >> 2, qa1 = (c1 & 3) ^ ((c1 >> 3) & 3);
  const uint16_t* Ag0 = A  + (size_t)(bm * 128 + ra0) * lda + qa0 * 8;
  const uint16_t* Ag1 = A  + (size_t)(bm * 128 + ra1) * lda + qa1 * 8;
  const uint16_t* Bg0 = Bt + (size_t)(bn * 64 + ra0) * ldb + qa0 * 8;  // B: 256 chunks
  uint16_t* Al0 = As + c0 * 8; uint16_t* Al1 = As + c1 * 8;
  uint16_t* Bl0 = Bs + c0 * 8;

  f32x4 acc[4][2] = {};

  for (int k0 = 0; k0 < kmax; k0 += BK) {
    __syncthreads();
    gload_lds16(Ag0 + k0, Al0);
    gload_lds16(Ag1 + k0, Al1);
    gload_lds16(Bg0 + k0, Bl0);
    __syncthreads();
    short8 af[4], bfr[2];
#pragma unroll
    for (int i = 0; i < 4; ++i) {
      int r = wm + i * 16 + lr;
      af[i] = *(const short8*)(&As[(r * 4 + (quad ^ ((r >> 1) & 3))) * 8]);
    }
#pragma unroll
    for (int j = 0; j < 2; ++j) {
      int r = wn + j * 16 + lr;
      bfr[j] = *(const short8*)(&Bs[(r * 4 + (quad ^ ((r >> 1) & 3))) * 8]);
    }
#pragma unroll
    for (int i = 0; i < 4; ++i)
#pragma unroll
      for (int j = 0; j < 2; ++j)
        acc[i][j] = __builtin_amdgcn_mfma_f32_16x16x32_bf16(af[i], bfr[j], acc[i][j], 0, 0, 0);
  }

  int row0 = bm * 128 + wm + quad * 4;
  int col0 = bn * 64 + wn + lr;
#pragma unroll
  for (int j = 0; j < 2; ++j) {
    int col = col0 + j * 16;
    float bv = bias ? bias[col] : 0.0f;
#pragma unroll
    for (int i = 0; i < 4; ++i) {
#pragma unroll
      for (int r = 0; r < 4; ++r) {
        int row = row0 + i * 16 + r;
        float v = acc[i][j][r] * scale + bv;
        if (relu) v = fmaxf(v, 0.0f);
        size_t idx = (size_t)row * ldc + col;
        if (out_bf16) ((uint16_t*)Cout)[idx] = f2bf(v);
        else          ((float*)Cout)[idx]    = v;
      }
    }
  }
}

// ---------------- reductions ------------------------------------------------
__device__ __forceinline__ float block_sum(float v, float* red) {
#pragma unroll
  for (int o = 32; o > 0; o >>= 1) v += __shfl_xor(v, o, 64);
  if ((threadIdx.x & 63) == 0) red[threadIdx.x >> 6] = v;
  __syncthreads();
  v = red[0] + red[1] + red[2] + red[3];
  __syncthreads();
  return v;
}
__device__ __forceinline__ float block_max(float v, float* red) {
#pragma unroll
  for (int o = 32; o > 0; o >>= 1) v = fmaxf(v, __shfl_xor(v, o, 64));
  if ((threadIdx.x & 63) == 0) red[threadIdx.x >> 6] = v;
  __syncthreads();
  v = fmaxf(fmaxf(red[0], red[1]), fmaxf(red[2], red[3]));
  __syncthreads();
  return v;
}

// ---------------- causal softmax, in-place fp32 S -> bf16 A -----------------
__global__ __launch_bounds__(256) void softmax_causal(float* __restrict__ S) {
  __shared__ float red[4];
  int i = blockIdx.x, tid = threadIdx.x;
  float* srow = S + (size_t)i * 4096;
  uint16_t* arow = (uint16_t*)srow;
  int lim = ((i >> 7) + 1) << 7;
  float v[16];
  float mx = -3.4e38f;
#pragma unroll
  for (int it = 0; it < 16; ++it) {
    int j = it * 256 + tid;
    float x = -3.4e38f;
    if (j <= i) x = srow[j];
    v[it] = x;
    mx = fmaxf(mx, x);
  }
  mx = block_max(mx, red);                 // barrier: all reads complete here
  float sum = 0.0f;
#pragma unroll
  for (int it = 0; it < 16; ++it) {
    float e = __expf(v[it] - mx);
    v[it] = e;
    sum += e;
  }
  sum = block_sum(sum, red);
  float inv = 1.0f / sum;
#pragma unroll
  for (int it = 0; it < 16; ++it) {
    int j = it * 256 + tid;
    if (j < lim) arow[j] = f2bf(v[it] * inv);
  }
}

// ---------------- residual add + LayerNorm -> bf16 --------------------------
__global__ __launch_bounds__(256) void add_layernorm(
    const float* __restrict__ O, const float* __restrict__ emb,
    const float* __restrict__ gamma, const float* __restrict__ beta,
    uint16_t* __restrict__ xB)
{
  __shared__ float red[4];
  int i = blockIdx.x, tid = threadIdx.x;
  float4 a = ((const float4*)(O   + (size_t)i * 1024))[tid];
  float4 b = ((const float4*)(emb + (size_t)i * 1024))[tid];
  float x0 = a.x + b.x, x1 = a.y + b.y, x2 = a.z + b.z, x3 = a.w + b.w;
  float mu = block_sum(x0 + x1 + x2 + x3, red) * (1.0f / 1024.0f);
  float d0 = x0 - mu, d1 = x1 - mu, d2 = x2 - mu, d3 = x3 - mu;
  float var = block_sum(d0 * d0 + d1 * d1 + d2 * d2 + d3 * d3, red) * (1.0f / 1024.0f);
  float rs = rsqrtf(var + 1e-5f);
  float4 g  = ((const float4*)gamma)[tid];
  float4 be = ((const float4*)beta)[tid];
  ushort4 o;
  o.x = f2bf(d0 * rs * g.x + be.x);
  o.y = f2bf(d1 * rs * g.y + be.y);
  o.z = f2bf(d2 * rs * g.z + be.z);
  o.w = f2bf(d3 * rs * g.w + be.w);
  ((ushort4*)(xB + (size_t)i * 1024))[tid] = o;
}

// ---------------- casts / transposes / bias pack ----------------------------
__global__ __launch_bounds__(256) void cast_f32_bf16(
    const float* __restrict__ in, uint16_t* __restrict__ out, int n4)
{
  int idx = blockIdx.x * 256 + threadIdx.x;
  if (idx >= n4) return;
  float4 v = ((const float4*)in)[idx];
  ushort4 o; o.x = f2bf(v.x); o.y = f2bf(v.y); o.z = f2bf(v.z); o.w = f2bf(v.w);
  ((ushort4*)out)[idx] = o;
}

__global__ __launch_bounds__(256) void cast_transpose(
    const float* __restrict__ in, uint16_t* __restrict__ out, int R, int C)
{
  __shared__ float tile[32][33];
  int tx = threadIdx.x & 31, ty = threadIdx.x >> 5;
  int r0 = blockIdx.y * 32, c0 = blockIdx.x * 32;
#pragma unroll
  for (int r = 0; r < 32; r += 8)
    tile[ty + r][tx] = in[(size_t)(r0 + ty + r) * C + c0 + tx];
  __syncthreads();
#pragma unroll
  for (int r = 0; r < 32; r += 8)
    out[(size_t)(c0 + ty + r) * R + r0 + tx] = f2bf(tile[tx][ty + r]);
}

// bf16 [R,C] (row stride ldin) -> bf16 [C,R]
__global__ __launch_bounds__(256) void transpose_u16(
    const uint16_t* __restrict__ in, uint16_t* __restrict__ out, int R, int C, int ldin)
{
  __shared__ uint16_t tile[32][33];
  int tx = threadIdx.x & 31, ty = threadIdx.x >> 5;
  int r0 = blockIdx.y * 32, c0 = blockIdx.x * 32;
#pragma unroll
  for (int r = 0; r < 32; r += 8)
    tile[ty + r][tx] = in[(size_t)(r0 + ty + r) * ldin + c0 + tx];
  __syncthreads();
#pragma unroll
  for (int r = 0; r < 32; r += 8)
    out[(size_t)(c0 + ty + r) * R + r0 + tx] = tile[tx][ty + r];
}

__global__ __launch_bounds__(256) void pack_bias3(
    const float* __restrict__ b0, const float* __restrict__ b1,
    const float* __restrict__ b2, float* __restrict__ out)
{
  int i = blockIdx.x * 256 + threadIdx.x;   // 3072 threads
  float v = (i < 1024) ? b0[i] : (i < 2048) ? b1[i - 1024] : b2[i - 2048];
  out[i] = v;
}

// ---------------- launcher --------------------------------------------------
extern "C" void kernel_launch(void* const* d_in, const int* in_sizes, int n_in,
                              void* d_out, int out_size, void* d_ws, size_t ws_size,
                              hipStream_t stream) {
  const float* emb   = (const float*)d_in[0];
  const float* Wq    = (const float*)d_in[1];
  const float* bq    = (const float*)d_in[2];
  const float* Wk    = (const float*)d_in[3];
  const float* bk    = (const float*)d_in[4];
  const float* Wv    = (const float*)d_in[5];
  const float* bv    = (const float*)d_in[6];
  const float* gamma = (const float*)d_in[7];
  const float* beta  = (const float*)d_in[8];
  const float* W1    = (const float*)d_in[9];
  const float* b1    = (const float*)d_in[10];
  const float* W2    = (const float*)d_in[11];
  const float* b2    = (const float*)d_in[12];

  char* w = (char*)d_ws;
  const size_t MB = 1ull << 20;
  uint16_t* embB  = (uint16_t*)(w + 0 * MB);    // [4096,1024] bf16 (freed after QKV)
  uint16_t* WqkvT = (uint16_t*)(w + 8 * MB);    // [3072,1024] packed q|k|v
  uint16_t* W1T   = (uint16_t*)(w + 14 * MB);   // [4096,1024]
  uint16_t* W2T   = (uint16_t*)(w + 22 * MB);   // [1024,4096]
  float*    bqkv  = (float*)(w + 30 * MB);      // [3072]
  uint16_t* QKVb  = (uint16_t*)(w + 31 * MB);   // [4096,3072]
  uint16_t* Vt    = (uint16_t*)(w + 55 * MB);   // [1024,4096]
  uint16_t* xB    = (uint16_t*)(w + 0 * MB);    // reuses embB slot
  uint16_t* hB    = (uint16_t*)(w + 63 * MB);   // [4096,4096]
  float*    S     = (float*)(w + 95 * MB);      // [4096,4096] fp32 -> bf16 A
  // total ws requirement: 159 MB

  cast_f32_bf16 <<<4096, 256, 0, stream>>>(emb, embB, 1024 * 1024);
  cast_transpose<<<dim3(32, 32),  256, 0, stream>>>(Wq, WqkvT,                1024, 1024);
  cast_transpose<<<dim3(32, 32),  256, 0, stream>>>(Wk, WqkvT + 1024 * 1024,  1024, 1024);
  cast_transpose<<<dim3(32, 32),  256, 0, stream>>>(Wv, WqkvT + 2048 * 1024,  1024, 1024);
  cast_transpose<<<dim3(128, 32), 256, 0, stream>>>(W1, W1T, 1024, 4096);
  cast_transpose<<<dim3(32, 128), 256, 0, stream>>>(W2, W2T, 4096, 1024);
  pack_bias3    <<<12, 256, 0, stream>>>(bq, bk, bv, bqkv);

  // fused QKV: [4096,3072] = embB @ WqkvT^T, grid 768 (3 blocks/CU)
  gemm_bt<<<dim3(24, 32), 256, 0, stream>>>(embB, WqkvT, bqkv, QKVb,
      1024, 1024, 1024, 3072, 1.0f, 1, 0, 0);
  const uint16_t* Qb = QKVb;
  const uint16_t* Kb = QKVb + 1024;
  const uint16_t* Vb = QKVb + 2048;
  transpose_u16<<<dim3(32, 128), 256, 0, stream>>>(Vb, Vt, 4096, 1024, 3072);

  // S = QK^T/sqrt(D), lower-triangle blocks only (528-block launch)
  gemm_bt<<<528, 256, 0, stream>>>(Qb, Kb, nullptr, S,
      1024, 3072, 3072, 4096, 0.03125f, 0, 0, 1);
  softmax_causal<<<4096, 256, 0, stream>>>(S);
  // O = A @ V  (k-limited causal), 512 blocks, balanced bm remap
  gemm_bt_n64<<<dim3(16, 32), 256, 0, stream>>>((const uint16_t*)S, Vt, nullptr, d_out,
      4096, 8192, 4096, 1024, 1.0f, 0, 0, 2);

  add_layernorm<<<4096, 256, 0, stream>>>((const float*)d_out, emb, gamma, beta, xB);
  gemm_bt<<<dim3(32, 32), 256, 0, stream>>>(xB, W1T, b1, hB,
      1024, 1024, 1024, 4096, 1.0f, 1, 1, 0);
  gemm_bt_n64<<<dim3(16, 32), 256, 0, stream>>>(hB, W2T, b2, (float*)d_out,
      4096, 4096, 4096, 1024, 1.0f, 0, 0, 0);
}

// Round 3
// 461.007 us; speedup vs baseline: 1.1438x; 1.0266x over previous
//
#include <hip/hip_runtime.h>
#include <stdint.h>

// Round 3: split-K=2 on every grid<1024 GEMM (QKV, O, FFN2) with fp32
// partials in dead ws regions + fused reduces (no atomics). LDS swizzle
// (round 2, conflict-free) retained. Workspace requirement: 159 MB.

using short8 = __attribute__((ext_vector_type(8))) short;
using f32x4  = __attribute__((ext_vector_type(4))) float;

__device__ __forceinline__ uint16_t f2bf(float f) {
  uint32_t u = __builtin_bit_cast(uint32_t, f);
  u += 0x7FFFu + ((u >> 16) & 1u);        // RNE, inputs are finite
  return (uint16_t)(u >> 16);
}

__device__ __forceinline__ void gload_lds16(const uint16_t* g, uint16_t* l) {
  __builtin_amdgcn_global_load_lds(
      (__attribute__((address_space(1))) void*)(void*)g,
      (__attribute__((address_space(3))) void*)l, 16, 0, 0);
}

// LDS swizzle: 16B slot s holds chunk-col (s&3)^((s>>3)&3) of row s>>2.
// Read (row r, chunk q) -> slot r*4 + (q ^ ((r>>1)&3)). Conflict-free (R2).

// ---------------- GEMM 128x128: C = scale*A@Bt^T + bias ---------------------
// mode 0: 2-D grid. mode 1: triangular causal-S (1-D grid 528).
// mode 3: split-K=2, grid (N/128, 2*M/128), fp32 partials at half*4096*ldc.
__global__ __launch_bounds__(256) void gemm_bt(
    const uint16_t* __restrict__ A, const uint16_t* __restrict__ Bt,
    const float* __restrict__ bias, void* __restrict__ Cout,
    int K, int lda, int ldb, int ldc,
    float scale, int out_bf16, int relu, int mode)
{
  constexpr int BK = 32;
  __shared__ uint16_t As[128 * BK];
  __shared__ uint16_t Bs[128 * BK];
  int bm, bn, half = 0, klo = 0, khi = K;
  if (mode == 1) {                         // decode t -> lower-triangle (bm,bn)
    int t = blockIdx.x;
    bm = (int)((sqrtf(8.0f * (float)t + 1.0f) - 1.0f) * 0.5f);
    while ((bm + 1) * (bm + 2) / 2 <= t) ++bm;
    while (bm * (bm + 1) / 2 > t) --bm;
    bn = t - bm * (bm + 1) / 2;
  } else if (mode == 3) {
    bn = blockIdx.x; bm = blockIdx.y >> 1; half = blockIdx.y & 1;
    int mid = K >> 1; klo = half ? mid : 0; khi = half ? K : mid;
  } else {
    bm = blockIdx.y; bn = blockIdx.x;
  }

  int tid  = threadIdx.x;
  int lane = tid & 63;
  int wave = tid >> 6;
  int wm = (wave >> 1) * 64, wn = (wave & 1) * 64;
  int lr = lane & 15, quad = lane >> 4;

  int c0 = tid, c1 = tid + 256;
  int ra0 = c0 >> 2, qa0 = (c0 & 3) ^ ((c0 >> 3) & 3);
  int ra1 = c1 >> 2, qa1 = (c1 & 3) ^ ((c1 >> 3) & 3);
  const uint16_t* Ag0 = A  + (size_t)(bm * 128 + ra0) * lda + qa0 * 8;
  const uint16_t* Ag1 = A  + (size_t)(bm * 128 + ra1) * lda + qa1 * 8;
  const uint16_t* Bg0 = Bt + (size_t)(bn * 128 + ra0) * ldb + qa0 * 8;
  const uint16_t* Bg1 = Bt + (size_t)(bn * 128 + ra1) * ldb + qa1 * 8;
  uint16_t* Al0 = As + c0 * 8; uint16_t* Al1 = As + c1 * 8;
  uint16_t* Bl0 = Bs + c0 * 8; uint16_t* Bl1 = Bs + c1 * 8;

  f32x4 acc[4][4] = {};

  for (int k0 = klo; k0 < khi; k0 += BK) {
    __syncthreads();
    gload_lds16(Ag0 + k0, Al0);
    gload_lds16(Ag1 + k0, Al1);
    gload_lds16(Bg0 + k0, Bl0);
    gload_lds16(Bg1 + k0, Bl1);
    __syncthreads();
    short8 af[4], bfr[4];
#pragma unroll
    for (int i = 0; i < 4; ++i) {
      int r = wm + i * 16 + lr;
      af[i] = *(const short8*)(&As[(r * 4 + (quad ^ ((r >> 1) & 3))) * 8]);
    }
#pragma unroll
    for (int j = 0; j < 4; ++j) {
      int r = wn + j * 16 + lr;
      bfr[j] = *(const short8*)(&Bs[(r * 4 + (quad ^ ((r >> 1) & 3))) * 8]);
    }
#pragma unroll
    for (int i = 0; i < 4; ++i)
#pragma unroll
      for (int j = 0; j < 4; ++j)
        acc[i][j] = __builtin_amdgcn_mfma_f32_16x16x32_bf16(af[i], bfr[j], acc[i][j], 0, 0, 0);
  }

  void* Cw = (mode == 3) ? (void*)((float*)Cout + (size_t)half * 4096 * ldc) : Cout;
  int row0 = bm * 128 + wm + quad * 4;
  int col0 = bn * 128 + wn + lr;
#pragma unroll
  for (int j = 0; j < 4; ++j) {
    int col = col0 + j * 16;
    float bv = bias ? bias[col] : 0.0f;
#pragma unroll
    for (int i = 0; i < 4; ++i) {
#pragma unroll
      for (int r = 0; r < 4; ++r) {
        int row = row0 + i * 16 + r;
        float v = acc[i][j][r] * scale + bv;
        if (relu) v = fmaxf(v, 0.0f);
        size_t idx = (size_t)row * ldc + col;
        if (out_bf16) ((uint16_t*)Cw)[idx] = f2bf(v);
        else          ((float*)Cw)[idx]    = v;
      }
    }
  }
}

// ---------------- GEMM 128x64 (N=1024 outputs) ------------------------------
// mode 2: split-K=2 causal-O (grid y=64: t=y>>1 balanced-remap, half=y&1,
//         K range = halves of (bm+1)*128). mode 3: split-K=2 full.
// Split modes write fp32 partials at half*4096*ldc (no bias/relu/scale!=1).
__global__ __launch_bounds__(256) void gemm_bt_n64(
    const uint16_t* __restrict__ A, const uint16_t* __restrict__ Bt,
    const float* __restrict__ bias, void* __restrict__ Cout,
    int K, int lda, int ldb, int ldc,
    float scale, int out_bf16, int relu, int mode)
{
  constexpr int BK = 32;
  __shared__ uint16_t As[128 * BK];
  __shared__ uint16_t Bs[64 * BK];
  int bn = blockIdx.x, b = blockIdx.y;
  int bm, half = 0, klo = 0, khi = K;
  if (mode == 2) {
    int t = b >> 1; half = b & 1;
    bm = (t & 1) ? (t >> 1) : (31 - (t >> 1));       // long bm's early
    int kmax = (bm + 1) << 7, mid = kmax >> 1;       // mid multiple of 64
    klo = half ? mid : 0; khi = half ? kmax : mid;
  } else if (mode == 3) {
    bm = b >> 1; half = b & 1;
    int mid = K >> 1; klo = half ? mid : 0; khi = half ? K : mid;
  } else {
    bm = b;
  }

  int tid  = threadIdx.x;
  int lane = tid & 63;
  int wave = tid >> 6;
  int wm = (wave & 1) * 64, wn = (wave >> 1) * 32;   // wave: 64 rows x 32 cols
  int lr = lane & 15, quad = lane >> 4;

  int c0 = tid, c1 = tid + 256;
  int ra0 = c0 >> 2, qa0 = (c0 & 3) ^ ((c0 >> 3) & 3);
  int ra1 = c1 >> 2, qa1 = (c1 & 3) ^ ((c1 >> 3) & 3);
  const uint16_t* Ag0 = A  + (size_t)(bm * 128 + ra0) * lda + qa0 * 8;
  const uint16_t* Ag1 = A  + (size_t)(bm * 128 + ra1) * lda + qa1 * 8;
  const uint16_t* Bg0 = Bt + (size_t)(bn * 64 + ra0) * ldb + qa0 * 8;
  uint16_t* Al0 = As + c0 * 8; uint16_t* Al1 = As + c1 * 8;
  uint16_t* Bl0 = Bs + c0 * 8;

  f32x4 acc[4][2] = {};

  for (int k0 = klo; k0 < khi; k0 += BK) {
    __syncthreads();
    gload_lds16(Ag0 + k0, Al0);
    gload_lds16(Ag1 + k0, Al1);
    gload_lds16(Bg0 + k0, Bl0);
    __syncthreads();
    short8 af[4], bfr[2];
#pragma unroll
    for (int i = 0; i < 4; ++i) {
      int r = wm + i * 16 + lr;
      af[i] = *(const short8*)(&As[(r * 4 + (quad ^ ((r >> 1) & 3))) * 8]);
    }
#pragma unroll
    for (int j = 0; j < 2; ++j) {
      int r = wn + j * 16 + lr;
      bfr[j] = *(const short8*)(&Bs[(r * 4 + (quad ^ ((r >> 1) & 3))) * 8]);
    }
#pragma unroll
    for (int i = 0; i < 4; ++i)
#pragma unroll
      for (int j = 0; j < 2; ++j)
        acc[i][j] = __builtin_amdgcn_mfma_f32_16x16x32_bf16(af[i], bfr[j], acc[i][j], 0, 0, 0);
  }

  void* Cw = (mode >= 2) ? (void*)((float*)Cout + (size_t)half * 4096 * ldc) : Cout;
  int row0 = bm * 128 + wm + quad * 4;
  int col0 = bn * 64 + wn + lr;
#pragma unroll
  for (int j = 0; j < 2; ++j) {
    int col = col0 + j * 16;
    float bv = bias ? bias[col] : 0.0f;
#pragma unroll
    for (int i = 0; i < 4; ++i) {
#pragma unroll
      for (int r = 0; r < 4; ++r) {
        int row = row0 + i * 16 + r;
        float v = acc[i][j][r] * scale + bv;
        if (relu) v = fmaxf(v, 0.0f);
        size_t idx = (size_t)row * ldc + col;
        if (out_bf16) ((uint16_t*)Cw)[idx] = f2bf(v);
        else          ((float*)Cw)[idx]    = v;
      }
    }
  }
}

// ---------------- reductions ------------------------------------------------
__device__ __forceinline__ float block_sum(float v, float* red) {
#pragma unroll
  for (int o = 32; o > 0; o >>= 1) v += __shfl_xor(v, o, 64);
  if ((threadIdx.x & 63) == 0) red[threadIdx.x >> 6] = v;
  __syncthreads();
  v = red[0] + red[1] + red[2] + red[3];
  __syncthreads();
  return v;
}
__device__ __forceinline__ float block_max(float v, float* red) {
#pragma unroll
  for (int o = 32; o > 0; o >>= 1) v = fmaxf(v, __shfl_xor(v, o, 64));
  if ((threadIdx.x & 63) == 0) red[threadIdx.x >> 6] = v;
  __syncthreads();
  v = fmaxf(fmaxf(red[0], red[1]), fmaxf(red[2], red[3]));
  __syncthreads();
  return v;
}

// ---------------- causal softmax, in-place fp32 S -> bf16 A -----------------
__global__ __launch_bounds__(256) void softmax_causal(float* __restrict__ S) {
  __shared__ float red[4];
  int i = blockIdx.x, tid = threadIdx.x;
  float* srow = S + (size_t)i * 4096;
  uint16_t* arow = (uint16_t*)srow;
  int lim = ((i >> 7) + 1) << 7;
  float v[16];
  float mx = -3.4e38f;
#pragma unroll
  for (int it = 0; it < 16; ++it) {
    int j = it * 256 + tid;
    float x = -3.4e38f;
    if (j <= i) x = srow[j];
    v[it] = x;
    mx = fmaxf(mx, x);
  }
  mx = block_max(mx, red);                 // barrier: all reads complete here
  float sum = 0.0f;
#pragma unroll
  for (int it = 0; it < 16; ++it) {
    float e = __expf(v[it] - mx);
    v[it] = e;
    sum += e;
  }
  sum = block_sum(sum, red);
  float inv = 1.0f / sum;
#pragma unroll
  for (int it = 0; it < 16; ++it) {
    int j = it * 256 + tid;
    if (j < lim) arow[j] = f2bf(v[it] * inv);
  }
}

// ---------------- O-partials reduce + residual + LayerNorm -> bf16 ----------
__global__ __launch_bounds__(256) void add_layernorm(
    const float* __restrict__ P, const float* __restrict__ emb,
    const float* __restrict__ gamma, const float* __restrict__ beta,
    uint16_t* __restrict__ xB)
{
  __shared__ float red[4];
  int i = blockIdx.x, tid = threadIdx.x;
  float4 a0 = ((const float4*)(P + (size_t)i * 1024))[tid];
  float4 a1 = ((const float4*)(P + 4194304 + (size_t)i * 1024))[tid];
  float4 b  = ((const float4*)(emb + (size_t)i * 1024))[tid];
  float x0 = a0.x + a1.x + b.x, x1 = a0.y + a1.y + b.y;
  float x2 = a0.z + a1.z + b.z, x3 = a0.w + a1.w + b.w;
  float mu = block_sum(x0 + x1 + x2 + x3, red) * (1.0f / 1024.0f);
  float d0 = x0 - mu, d1 = x1 - mu, d2 = x2 - mu, d3 = x3 - mu;
  float var = block_sum(d0 * d0 + d1 * d1 + d2 * d2 + d3 * d3, red) * (1.0f / 1024.0f);
  float rs = rsqrtf(var + 1e-5f);
  float4 g  = ((const float4*)gamma)[tid];
  float4 be = ((const float4*)beta)[tid];
  ushort4 o;
  o.x = f2bf(d0 * rs * g.x + be.x);
  o.y = f2bf(d1 * rs * g.y + be.y);
  o.z = f2bf(d2 * rs * g.z + be.z);
  o.w = f2bf(d3 * rs * g.w + be.w);
  ((ushort4*)(xB + (size_t)i * 1024))[tid] = o;
}

// ---------------- FFN2-partials reduce + bias -> fp32 d_out -----------------
__global__ __launch_bounds__(256) void reduce2_bias(
    const float* __restrict__ P, const float* __restrict__ bias,
    float* __restrict__ out)
{
  int i = blockIdx.x, tid = threadIdx.x;
  float4 a = ((const float4*)(P + (size_t)i * 1024))[tid];
  float4 c = ((const float4*)(P + 4194304 + (size_t)i * 1024))[tid];
  float4 bv = ((const float4*)bias)[tid];
  float4 o;
  o.x = a.x + c.x + bv.x; o.y = a.y + c.y + bv.y;
  o.z = a.z + c.z + bv.z; o.w = a.w + c.w + bv.w;
  ((float4*)(out + (size_t)i * 1024))[tid] = o;
}

// ---------------- QKV-partials reduce + bias -> bf16 QKVb -------------------
__global__ __launch_bounds__(256) void reduce2_qkv(
    const float* __restrict__ P, const float* __restrict__ bias,
    uint16_t* __restrict__ out)
{
  int i = blockIdx.x, tid = threadIdx.x;
  const float* r0 = P + (size_t)i * 3072;
  const float* r1 = r0 + 12582912;         // 4096*3072
  uint16_t* orow = out + (size_t)i * 3072;
#pragma unroll
  for (int it = 0; it < 3; ++it) {
    int c4 = it * 256 + tid;
    float4 a = ((const float4*)r0)[c4];
    float4 b = ((const float4*)r1)[c4];
    float4 bv = ((const float4*)bias)[c4];
    ushort4 o;
    o.x = f2bf(a.x + b.x + bv.x); o.y = f2bf(a.y + b.y + bv.y);
    o.z = f2bf(a.z + b.z + bv.z); o.w = f2bf(a.w + b.w + bv.w);
    ((ushort4*)orow)[c4] = o;
  }
}

// ---------------- casts / transposes / bias pack ----------------------------
__global__ __launch_bounds__(256) void cast_f32_bf16(
    const float* __restrict__ in, uint16_t* __restrict__ out, int n4)
{
  int idx = blockIdx.x * 256 + threadIdx.x;
  if (idx >= n4) return;
  float4 v = ((const float4*)in)[idx];
  ushort4 o; o.x = f2bf(v.x); o.y = f2bf(v.y); o.z = f2bf(v.z); o.w = f2bf(v.w);
  ((ushort4*)out)[idx] = o;
}

__global__ __launch_bounds__(256) void cast_transpose(
    const float* __restrict__ in, uint16_t* __restrict__ out, int R, int C)
{
  __shared__ float tile[32][33];
  int tx = threadIdx.x & 31, ty = threadIdx.x >> 5;
  int r0 = blockIdx.y * 32, c0 = blockIdx.x * 32;
#pragma unroll
  for (int r = 0; r < 32; r += 8)
    tile[ty + r][tx] = in[(size_t)(r0 + ty + r) * C + c0 + tx];
  __syncthreads();
#pragma unroll
  for (int r = 0; r < 32; r += 8)
    out[(size_t)(c0 + ty + r) * R + r0 + tx] = f2bf(tile[tx][ty + r]);
}

// three 1024x1024 weight transposes in one launch (z = which matrix)
__global__ __launch_bounds__(256) void cast_transpose_qkv(
    const float* __restrict__ Wq, const float* __restrict__ Wk,
    const float* __restrict__ Wv, uint16_t* __restrict__ out)
{
  __shared__ float tile[32][33];
  const float* in = (blockIdx.z == 0) ? Wq : (blockIdx.z == 1) ? Wk : Wv;
  uint16_t* o = out + (size_t)blockIdx.z * 1048576;
  int tx = threadIdx.x & 31, ty = threadIdx.x >> 5;
  int r0 = blockIdx.y * 32, c0 = blockIdx.x * 32;
#pragma unroll
  for (int r = 0; r < 32; r += 8)
    tile[ty + r][tx] = in[(size_t)(r0 + ty + r) * 1024 + c0 + tx];
  __syncthreads();
#pragma unroll
  for (int r = 0; r < 32; r += 8)
    o[(size_t)(c0 + ty + r) * 1024 + r0 + tx] = f2bf(tile[tx][ty + r]);
}

// bf16 [R,C] (row stride ldin) -> bf16 [C,R]
__global__ __launch_bounds__(256) void transpose_u16(
    const uint16_t* __restrict__ in, uint16_t* __restrict__ out, int R, int C, int ldin)
{
  __shared__ uint16_t tile[32][33];
  int tx = threadIdx.x & 31, ty = threadIdx.x >> 5;
  int r0 = blockIdx.y * 32, c0 = blockIdx.x * 32;
#pragma unroll
  for (int r = 0; r < 32; r += 8)
    tile[ty + r][tx] = in[(size_t)(r0 + ty + r) * ldin + c0 + tx];
  __syncthreads();
#pragma unroll
  for (int r = 0; r < 32; r += 8)
    out[(size_t)(c0 + ty + r) * R + r0 + tx] = tile[tx][ty + r];
}

__global__ __launch_bounds__(256) void pack_bias3(
    const float* __restrict__ b0, const float* __restrict__ b1,
    const float* __restrict__ b2, float* __restrict__ out)
{
  int i = blockIdx.x * 256 + threadIdx.x;   // 3072 threads
  float v = (i < 1024) ? b0[i] : (i < 2048) ? b1[i - 1024] : b2[i - 2048];
  out[i] = v;
}

// ---------------- launcher --------------------------------------------------
extern "C" void kernel_launch(void* const* d_in, const int* in_sizes, int n_in,
                              void* d_out, int out_size, void* d_ws, size_t ws_size,
                              hipStream_t stream) {
  const float* emb   = (const float*)d_in[0];
  const float* Wq    = (const float*)d_in[1];
  const float* bq    = (const float*)d_in[2];
  const float* Wk    = (const float*)d_in[3];
  const float* bk    = (const float*)d_in[4];
  const float* Wv    = (const float*)d_in[5];
  const float* bv    = (const float*)d_in[6];
  const float* gamma = (const float*)d_in[7];
  const float* beta  = (const float*)d_in[8];
  const float* W1    = (const float*)d_in[9];
  const float* b1    = (const float*)d_in[10];
  const float* W2    = (const float*)d_in[11];
  const float* b2    = (const float*)d_in[12];

  char* w = (char*)d_ws;
  const size_t MB = 1ull << 20;
  uint16_t* embB  = (uint16_t*)(w + 0 * MB);    // [4096,1024] bf16
  uint16_t* WqkvT = (uint16_t*)(w + 8 * MB);    // [3072,1024] packed q|k|v
  uint16_t* W1T   = (uint16_t*)(w + 14 * MB);   // [4096,1024]
  uint16_t* W2T   = (uint16_t*)(w + 22 * MB);   // [1024,4096]
  float*    bqkv  = (float*)(w + 30 * MB);      // [3072]
  uint16_t* QKVb  = (uint16_t*)(w + 31 * MB);   // [4096,3072]
  uint16_t* Vt    = (uint16_t*)(w + 55 * MB);   // [1024,4096]
  uint16_t* xB    = (uint16_t*)(w + 0 * MB);    // reuses embB (dead after QKV)
  uint16_t* hB    = (uint16_t*)(w + 63 * MB);   // [4096,4096] bf16
  float*    S     = (float*)(w + 95 * MB);      // [4096,4096] fp32 -> bf16 A
  float*    Qpart = (float*)(w + 63 * MB);      // [2][4096,3072] fp32 (96MB, pre-S)
  float*    Opart = (float*)(w + 63 * MB);      // [2][4096,1024] fp32 (32MB, pre-FFN1)
  float*    Fpart = (float*)(w + 95 * MB);      // [2][4096,1024] fp32 (reuses S)
  // total ws requirement: 159 MB

  cast_f32_bf16     <<<4096, 256, 0, stream>>>(emb, embB, 1024 * 1024);
  cast_transpose_qkv<<<dim3(32, 32, 3), 256, 0, stream>>>(Wq, Wk, Wv, WqkvT);
  cast_transpose    <<<dim3(128, 32), 256, 0, stream>>>(W1, W1T, 1024, 4096);
  cast_transpose    <<<dim3(32, 128), 256, 0, stream>>>(W2, W2T, 4096, 1024);
  pack_bias3        <<<12, 256, 0, stream>>>(bq, bk, bv, bqkv);

  // fused QKV, split-K=2: 1536 blocks, partials -> reduce(bias)+cast
  gemm_bt<<<dim3(24, 64), 256, 0, stream>>>(embB, WqkvT, nullptr, Qpart,
      1024, 1024, 1024, 3072, 1.0f, 0, 0, 3);
  reduce2_qkv<<<4096, 256, 0, stream>>>(Qpart, bqkv, QKVb);
  const uint16_t* Qb = QKVb;
  const uint16_t* Kb = QKVb + 1024;
  const uint16_t* Vb = QKVb + 2048;
  transpose_u16<<<dim3(32, 128), 256, 0, stream>>>(Vb, Vt, 4096, 1024, 3072);

  // S = QK^T/sqrt(D), lower-triangle blocks only (528-block launch)
  gemm_bt<<<528, 256, 0, stream>>>(Qb, Kb, nullptr, S,
      1024, 3072, 3072, 4096, 0.03125f, 0, 0, 1);
  softmax_causal<<<4096, 256, 0, stream>>>(S);
  // O = A @ V, causal split-K=2: 1024 blocks -> partials
  gemm_bt_n64<<<dim3(16, 64), 256, 0, stream>>>((const uint16_t*)S, Vt, nullptr, Opart,
      4096, 8192, 4096, 1024, 1.0f, 0, 0, 2);

  // reduce O partials + residual + LayerNorm -> xB
  add_layernorm<<<4096, 256, 0, stream>>>(Opart, emb, gamma, beta, xB);
  gemm_bt<<<dim3(32, 32), 256, 0, stream>>>(xB, W1T, b1, hB,
      1024, 1024, 1024, 4096, 1.0f, 1, 1, 0);
  // FFN2 split-K=2: 1024 blocks -> partials -> reduce(bias) -> d_out
  gemm_bt_n64<<<dim3(16, 64), 256, 0, stream>>>(hB, W2T, nullptr, Fpart,
      4096, 4096, 4096, 1024, 1.0f, 0, 0, 3);
  reduce2_bias<<<4096, 256, 0, stream>>>(Fpart, b2, (float*)d_out);
}

// Round 4
// 411.849 us; speedup vs baseline: 1.2804x; 1.1194x over previous
//
#include <hip/hip_runtime.h>
#include <stdint.h>

// Round 4: (a) softmax pass eliminated — S-gemm epilogue writes bf16
// exp(S/sqrt(D)) directly (shift-free softmax; logits bounded), rowsum_exp
// computes denominators, add_layernorm normalizes. fp32 S (138MB W + 64MB R)
// -> bf16 exp-S (34MB W + 17MB R). (b) BK=64 K-loop: half the barriers, 8
// in-flight global_load_lds per drain, 8-col XOR LDS swizzle. Split-K=2 on
// QKV/O/FFN2 retained. Workspace requirement: 159 MB.

using short8 = __attribute__((ext_vector_type(8))) short;
using f32x4  = __attribute__((ext_vector_type(4))) float;

__device__ __forceinline__ uint16_t f2bf(float f) {
  uint32_t u = __builtin_bit_cast(uint32_t, f);
  u += 0x7FFFu + ((u >> 16) & 1u);        // RNE, inputs are finite
  return (uint16_t)(u >> 16);
}

__device__ __forceinline__ void gload_lds16(const uint16_t* g, uint16_t* l) {
  __builtin_amdgcn_global_load_lds(
      (__attribute__((address_space(1))) void*)(void*)g,
      (__attribute__((address_space(3))) void*)l, 16, 0, 0);
}

// LDS swizzle (BK=64): 16B slot s holds global chunk-col (s&7)^((s>>3)&7) of
// row s>>3. Read (row r, chunk cc) -> slot r*8 + (cc ^ (r&7)).

// ---------------- GEMM 128x128: C = scale*A@Bt^T + bias ---------------------
// mode 0: 2-D grid. mode 1: triangular causal-S (1-D grid 528), epilogue
// writes bf16 exp(v) with causal mask. mode 3: split-K=2, fp32 partials at
// half*4096*ldc.
__global__ __launch_bounds__(256) void gemm_bt(
    const uint16_t* __restrict__ A, const uint16_t* __restrict__ Bt,
    const float* __restrict__ bias, void* __restrict__ Cout,
    int K, int lda, int ldb, int ldc,
    float scale, int out_bf16, int relu, int mode)
{
  constexpr int BK = 64;
  __shared__ uint16_t As[128 * BK];
  __shared__ uint16_t Bs[128 * BK];
  int bm, bn, half = 0, klo = 0, khi = K;
  if (mode == 1) {                         // decode t -> lower-triangle (bm,bn)
    int t = blockIdx.x;
    bm = (int)((sqrtf(8.0f * (float)t + 1.0f) - 1.0f) * 0.5f);
    while ((bm + 1) * (bm + 2) / 2 <= t) ++bm;
    while (bm * (bm + 1) / 2 > t) --bm;
    bn = t - bm * (bm + 1) / 2;
  } else if (mode == 3) {
    bn = blockIdx.x; bm = blockIdx.y >> 1; half = blockIdx.y & 1;
    int mid = K >> 1; klo = half ? mid : 0; khi = half ? K : mid;
  } else {
    bm = blockIdx.y; bn = blockIdx.x;
  }

  int tid  = threadIdx.x;
  int lane = tid & 63;
  int wave = tid >> 6;
  int wm = (wave >> 1) * 64, wn = (wave & 1) * 64;
  int lr = lane & 15, quad = lane >> 4;

  // staging: 1024 16B-chunks per matrix, 4 per thread, source-side swizzle
  const uint16_t *Ag[4], *Bg[4];
  uint16_t *Al[4], *Bl[4];
#pragma unroll
  for (int s = 0; s < 4; ++s) {
    int c = tid + 256 * s;
    int r = c >> 3, q = (c & 7) ^ (r & 7);
    Ag[s] = A  + (size_t)(bm * 128 + r) * lda + q * 8;
    Bg[s] = Bt + (size_t)(bn * 128 + r) * ldb + q * 8;
    Al[s] = As + c * 8;
    Bl[s] = Bs + c * 8;
  }

  f32x4 acc[4][4] = {};

  for (int k0 = klo; k0 < khi; k0 += BK) {
    __syncthreads();
#pragma unroll
    for (int s = 0; s < 4; ++s) gload_lds16(Ag[s] + k0, Al[s]);
#pragma unroll
    for (int s = 0; s < 4; ++s) gload_lds16(Bg[s] + k0, Bl[s]);
    __syncthreads();
#pragma unroll
    for (int h = 0; h < 2; ++h) {
      short8 af[4], bfr[4];
      int cc = quad + 4 * h;
#pragma unroll
      for (int i = 0; i < 4; ++i) {
        int r = wm + i * 16 + lr;
        af[i] = *(const short8*)(&As[(r * 8 + (cc ^ (r & 7))) * 8]);
      }
#pragma unroll
      for (int j = 0; j < 4; ++j) {
        int r = wn + j * 16 + lr;
        bfr[j] = *(const short8*)(&Bs[(r * 8 + (cc ^ (r & 7))) * 8]);
      }
#pragma unroll
      for (int i = 0; i < 4; ++i)
#pragma unroll
        for (int j = 0; j < 4; ++j)
          acc[i][j] = __builtin_amdgcn_mfma_f32_16x16x32_bf16(af[i], bfr[j], acc[i][j], 0, 0, 0);
    }
  }

  void* Cw = (mode == 3) ? (void*)((float*)Cout + (size_t)half * 4096 * ldc) : Cout;
  int row0 = bm * 128 + wm + quad * 4;
  int col0 = bn * 128 + wn + lr;
#pragma unroll
  for (int j = 0; j < 4; ++j) {
    int col = col0 + j * 16;
    float bv = bias ? bias[col] : 0.0f;
#pragma unroll
    for (int i = 0; i < 4; ++i) {
#pragma unroll
      for (int r = 0; r < 4; ++r) {
        int row = row0 + i * 16 + r;
        float v = acc[i][j][r] * scale + bv;
        if (relu) v = fmaxf(v, 0.0f);
        if (mode == 1) v = (col <= row) ? __expf(v) : 0.0f;  // shift-free softmax numerator
        size_t idx = (size_t)row * ldc + col;
        if (out_bf16) ((uint16_t*)Cw)[idx] = f2bf(v);
        else          ((float*)Cw)[idx]    = v;
      }
    }
  }
}

// ---------------- GEMM 128x64 (N=1024 outputs) ------------------------------
// mode 2: split-K=2 causal-O (grid y=64). mode 3: split-K=2 full.
// Split modes write fp32 partials at half*4096*ldc (no bias/relu/scale!=1).
__global__ __launch_bounds__(256) void gemm_bt_n64(
    const uint16_t* __restrict__ A, const uint16_t* __restrict__ Bt,
    const float* __restrict__ bias, void* __restrict__ Cout,
    int K, int lda, int ldb, int ldc,
    float scale, int out_bf16, int relu, int mode)
{
  constexpr int BK = 64;
  __shared__ uint16_t As[128 * BK];
  __shared__ uint16_t Bs[64 * BK];
  int bn = blockIdx.x, b = blockIdx.y;
  int bm, half = 0, klo = 0, khi = K;
  if (mode == 2) {
    int t = b >> 1; half = b & 1;
    bm = (t & 1) ? (t >> 1) : (31 - (t >> 1));       // long bm's early
    int kmax = (bm + 1) << 7, mid = kmax >> 1;       // mid multiple of 64
    klo = half ? mid : 0; khi = half ? kmax : mid;
  } else if (mode == 3) {
    bm = b >> 1; half = b & 1;
    int mid = K >> 1; klo = half ? mid : 0; khi = half ? K : mid;
  } else {
    bm = b;
  }

  int tid  = threadIdx.x;
  int lane = tid & 63;
  int wave = tid >> 6;
  int wm = (wave & 1) * 64, wn = (wave >> 1) * 32;   // wave: 64 rows x 32 cols
  int lr = lane & 15, quad = lane >> 4;

  const uint16_t *Ag[4], *Bg[2];
  uint16_t *Al[4], *Bl[2];
#pragma unroll
  for (int s = 0; s < 4; ++s) {
    int c = tid + 256 * s;
    int r = c >> 3, q = (c & 7) ^ (r & 7);
    Ag[s] = A + (size_t)(bm * 128 + r) * lda + q * 8;
    Al[s] = As + c * 8;
  }
#pragma unroll
  for (int s = 0; s < 2; ++s) {
    int c = tid + 256 * s;
    int r = c >> 3, q = (c & 7) ^ (r & 7);
    Bg[s] = Bt + (size_t)(bn * 64 + r) * ldb + q * 8;
    Bl[s] = Bs + c * 8;
  }

  f32x4 acc[4][2] = {};

  for (int k0 = klo; k0 < khi; k0 += BK) {
    __syncthreads();
#pragma unroll
    for (int s = 0; s < 4; ++s) gload_lds16(Ag[s] + k0, Al[s]);
#pragma unroll
    for (int s = 0; s < 2; ++s) gload_lds16(Bg[s] + k0, Bl[s]);
    __syncthreads();
#pragma unroll
    for (int h = 0; h < 2; ++h) {
      short8 af[4], bfr[2];
      int cc = quad + 4 * h;
#pragma unroll
      for (int i = 0; i < 4; ++i) {
        int r = wm + i * 16 + lr;
        af[i] = *(const short8*)(&As[(r * 8 + (cc ^ (r & 7))) * 8]);
      }
#pragma unroll
      for (int j = 0; j < 2; ++j) {
        int r = wn + j * 16 + lr;
        bfr[j] = *(const short8*)(&Bs[(r * 8 + (cc ^ (r & 7))) * 8]);
      }
#pragma unroll
      for (int i = 0; i < 4; ++i)
#pragma unroll
        for (int j = 0; j < 2; ++j)
          acc[i][j] = __builtin_amdgcn_mfma_f32_16x16x32_bf16(af[i], bfr[j], acc[i][j], 0, 0, 0);
    }
  }

  void* Cw = (mode >= 2) ? (void*)((float*)Cout + (size_t)half * 4096 * ldc) : Cout;
  int row0 = bm * 128 + wm + quad * 4;
  int col0 = bn * 64 + wn + lr;
#pragma unroll
  for (int j = 0; j < 2; ++j) {
    int col = col0 + j * 16;
    float bv = bias ? bias[col] : 0.0f;
#pragma unroll
    for (int i = 0; i < 4; ++i) {
#pragma unroll
      for (int r = 0; r < 4; ++r) {
        int row = row0 + i * 16 + r;
        float v = acc[i][j][r] * scale + bv;
        if (relu) v = fmaxf(v, 0.0f);
        size_t idx = (size_t)row * ldc + col;
        if (out_bf16) ((uint16_t*)Cw)[idx] = f2bf(v);
        else          ((float*)Cw)[idx]    = v;
      }
    }
  }
}

// ---------------- reductions ------------------------------------------------
__device__ __forceinline__ float block_sum(float v, float* red) {
#pragma unroll
  for (int o = 32; o > 0; o >>= 1) v += __shfl_xor(v, o, 64);
  if ((threadIdx.x & 63) == 0) red[threadIdx.x >> 6] = v;
  __syncthreads();
  v = red[0] + red[1] + red[2] + red[3];
  __syncthreads();
  return v;
}

// ---------------- row sums of exp-S (softmax denominators) ------------------
__global__ __launch_bounds__(256) void rowsum_exp(
    const uint16_t* __restrict__ Sb, float* __restrict__ l)
{
  __shared__ float red[4];
  int i = blockIdx.x, tid = threadIdx.x;
  const ushort4* row = (const ushort4*)(Sb + (size_t)i * 4096);
  int lim4 = (((i >> 7) + 1) << 7) >> 2;     // valid cols / 4 (zeros beyond i)
  float s = 0.0f;
  for (int c = tid; c < lim4; c += 256) {
    ushort4 u = row[c];
    s += __builtin_bit_cast(float, (uint32_t)u.x << 16)
       + __builtin_bit_cast(float, (uint32_t)u.y << 16)
       + __builtin_bit_cast(float, (uint32_t)u.z << 16)
       + __builtin_bit_cast(float, (uint32_t)u.w << 16);
  }
  s = block_sum(s, red);
  if (tid == 0) l[i] = s;
}

// ---------------- O-partials reduce /l + residual + LayerNorm -> bf16 -------
__global__ __launch_bounds__(256) void add_layernorm(
    const float* __restrict__ P, const float* __restrict__ l,
    const float* __restrict__ emb, const float* __restrict__ gamma,
    const float* __restrict__ beta, uint16_t* __restrict__ xB)
{
  __shared__ float red[4];
  int i = blockIdx.x, tid = threadIdx.x;
  float inv_l = 1.0f / l[i];
  float4 a0 = ((const float4*)(P + (size_t)i * 1024))[tid];
  float4 a1 = ((const float4*)(P + 4194304 + (size_t)i * 1024))[tid];
  float4 b  = ((const float4*)(emb + (size_t)i * 1024))[tid];
  float x0 = (a0.x + a1.x) * inv_l + b.x, x1 = (a0.y + a1.y) * inv_l + b.y;
  float x2 = (a0.z + a1.z) * inv_l + b.z, x3 = (a0.w + a1.w) * inv_l + b.w;
  float mu = block_sum(x0 + x1 + x2 + x3, red) * (1.0f / 1024.0f);
  float d0 = x0 - mu, d1 = x1 - mu, d2 = x2 - mu, d3 = x3 - mu;
  float var = block_sum(d0 * d0 + d1 * d1 + d2 * d2 + d3 * d3, red) * (1.0f / 1024.0f);
  float rs = rsqrtf(var + 1e-5f);
  float4 g  = ((const float4*)gamma)[tid];
  float4 be = ((const float4*)beta)[tid];
  ushort4 o;
  o.x = f2bf(d0 * rs * g.x + be.x);
  o.y = f2bf(d1 * rs * g.y + be.y);
  o.z = f2bf(d2 * rs * g.z + be.z);
  o.w = f2bf(d3 * rs * g.w + be.w);
  ((ushort4*)(xB + (size_t)i * 1024))[tid] = o;
}

// ---------------- FFN2-partials reduce + bias -> fp32 d_out -----------------
__global__ __launch_bounds__(256) void reduce2_bias(
    const float* __restrict__ P, const float* __restrict__ bias,
    float* __restrict__ out)
{
  int i = blockIdx.x, tid = threadIdx.x;
  float4 a = ((const float4*)(P + (size_t)i * 1024))[tid];
  float4 c = ((const float4*)(P + 4194304 + (size_t)i * 1024))[tid];
  float4 bv = ((const float4*)bias)[tid];
  float4 o;
  o.x = a.x + c.x + bv.x; o.y = a.y + c.y + bv.y;
  o.z = a.z + c.z + bv.z; o.w = a.w + c.w + bv.w;
  ((float4*)(out + (size_t)i * 1024))[tid] = o;
}

// ---------------- QKV-partials reduce + bias -> bf16 QKVb -------------------
__global__ __launch_bounds__(256) void reduce2_qkv(
    const float* __restrict__ P, const float* __restrict__ bias,
    uint16_t* __restrict__ out)
{
  int i = blockIdx.x, tid = threadIdx.x;
  const float* r0 = P + (size_t)i * 3072;
  const float* r1 = r0 + 12582912;         // 4096*3072
  uint16_t* orow = out + (size_t)i * 3072;
#pragma unroll
  for (int it = 0; it < 3; ++it) {
    int c4 = it * 256 + tid;
    float4 a = ((const float4*)r0)[c4];
    float4 b = ((const float4*)r1)[c4];
    float4 bv = ((const float4*)bias)[c4];
    ushort4 o;
    o.x = f2bf(a.x + b.x + bv.x); o.y = f2bf(a.y + b.y + bv.y);
    o.z = f2bf(a.z + b.z + bv.z); o.w = f2bf(a.w + b.w + bv.w);
    ((ushort4*)orow)[c4] = o;
  }
}

// ---------------- casts / transposes / bias pack ----------------------------
__global__ __launch_bounds__(256) void cast_f32_bf16(
    const float* __restrict__ in, uint16_t* __restrict__ out, int n4)
{
  int idx = blockIdx.x * 256 + threadIdx.x;
  if (idx >= n4) return;
  float4 v = ((const float4*)in)[idx];
  ushort4 o; o.x = f2bf(v.x); o.y = f2bf(v.y); o.z = f2bf(v.z); o.w = f2bf(v.w);
  ((ushort4*)out)[idx] = o;
}

__global__ __launch_bounds__(256) void cast_transpose(
    const float* __restrict__ in, uint16_t* __restrict__ out, int R, int C)
{
  __shared__ float tile[32][33];
  int tx = threadIdx.x & 31, ty = threadIdx.x >> 5;
  int r0 = blockIdx.y * 32, c0 = blockIdx.x * 32;
#pragma unroll
  for (int r = 0; r < 32; r += 8)
    tile[ty + r][tx] = in[(size_t)(r0 + ty + r) * C + c0 + tx];
  __syncthreads();
#pragma unroll
  for (int r = 0; r < 32; r += 8)
    out[(size_t)(c0 + ty + r) * R + r0 + tx] = f2bf(tile[tx][ty + r]);
}

// three 1024x1024 weight transposes in one launch (z = which matrix)
__global__ __launch_bounds__(256) void cast_transpose_qkv(
    const float* __restrict__ Wq, const float* __restrict__ Wk,
    const float* __restrict__ Wv, uint16_t* __restrict__ out)
{
  __shared__ float tile[32][33];
  const float* in = (blockIdx.z == 0) ? Wq : (blockIdx.z == 1) ? Wk : Wv;
  uint16_t* o = out + (size_t)blockIdx.z * 1048576;
  int tx = threadIdx.x & 31, ty = threadIdx.x >> 5;
  int r0 = blockIdx.y * 32, c0 = blockIdx.x * 32;
#pragma unroll
  for (int r = 0; r < 32; r += 8)
    tile[ty + r][tx] = in[(size_t)(r0 + ty + r) * 1024 + c0 + tx];
  __syncthreads();
#pragma unroll
  for (int r = 0; r < 32; r += 8)
    o[(size_t)(c0 + ty + r) * 1024 + r0 + tx] = f2bf(tile[tx][ty + r]);
}

// bf16 [R,C] (row stride ldin) -> bf16 [C,R]
__global__ __launch_bounds__(256) void transpose_u16(
    const uint16_t* __restrict__ in, uint16_t* __restrict__ out, int R, int C, int ldin)
{
  __shared__ uint16_t tile[32][33];
  int tx = threadIdx.x & 31, ty = threadIdx.x >> 5;
  int r0 = blockIdx.y * 32, c0 = blockIdx.x * 32;
#pragma unroll
  for (int r = 0; r < 32; r += 8)
    tile[ty + r][tx] = in[(size_t)(r0 + ty + r) * ldin + c0 + tx];
  __syncthreads();
#pragma unroll
  for (int r = 0; r < 32; r += 8)
    out[(size_t)(c0 + ty + r) * R + r0 + tx] = tile[tx][ty + r];
}

__global__ __launch_bounds__(256) void pack_bias3(
    const float* __restrict__ b0, const float* __restrict__ b1,
    const float* __restrict__ b2, float* __restrict__ out)
{
  int i = blockIdx.x * 256 + threadIdx.x;   // 3072 threads
  float v = (i < 1024) ? b0[i] : (i < 2048) ? b1[i - 1024] : b2[i - 2048];
  out[i] = v;
}

// ---------------- launcher --------------------------------------------------
extern "C" void kernel_launch(void* const* d_in, const int* in_sizes, int n_in,
                              void* d_out, int out_size, void* d_ws, size_t ws_size,
                              hipStream_t stream) {
  const float* emb   = (const float*)d_in[0];
  const float* Wq    = (const float*)d_in[1];
  const float* bq    = (const float*)d_in[2];
  const float* Wk    = (const float*)d_in[3];
  const float* bk    = (const float*)d_in[4];
  const float* Wv    = (const float*)d_in[5];
  const float* bv    = (const float*)d_in[6];
  const float* gamma = (const float*)d_in[7];
  const float* beta  = (const float*)d_in[8];
  const float* W1    = (const float*)d_in[9];
  const float* b1    = (const float*)d_in[10];
  const float* W2    = (const float*)d_in[11];
  const float* b2    = (const float*)d_in[12];

  char* w = (char*)d_ws;
  const size_t MB = 1ull << 20;
  uint16_t* embB  = (uint16_t*)(w + 0 * MB);    // [4096,1024] bf16
  uint16_t* WqkvT = (uint16_t*)(w + 8 * MB);    // [3072,1024] packed q|k|v
  uint16_t* W1T   = (uint16_t*)(w + 14 * MB);   // [4096,1024]
  uint16_t* W2T   = (uint16_t*)(w + 22 * MB);   // [1024,4096]
  float*    bqkv  = (float*)(w + 30 * MB);      // [3072]
  float*    lvec  = (float*)(w + 30 * MB + 65536); // [4096] softmax denominators
  uint16_t* QKVb  = (uint16_t*)(w + 31 * MB);   // [4096,3072]
  uint16_t* Vt    = (uint16_t*)(w + 55 * MB);   // [1024,4096]
  uint16_t* xB    = (uint16_t*)(w + 0 * MB);    // reuses embB (dead after QKV)
  uint16_t* hB    = (uint16_t*)(w + 63 * MB);   // [4096,4096] bf16
  uint16_t* Sb    = (uint16_t*)(w + 95 * MB);   // [4096,4096] bf16 exp(S)
  float*    Qpart = (float*)(w + 63 * MB);      // [2][4096,3072] fp32 (pre-S)
  float*    Opart = (float*)(w + 63 * MB);      // [2][4096,1024] fp32 (pre-FFN1)
  float*    Fpart = (float*)(w + 127 * MB);     // [2][4096,1024] fp32
  // total ws requirement: 159 MB

  cast_f32_bf16     <<<4096, 256, 0, stream>>>(emb, embB, 1024 * 1024);
  cast_transpose_qkv<<<dim3(32, 32, 3), 256, 0, stream>>>(Wq, Wk, Wv, WqkvT);
  cast_transpose    <<<dim3(128, 32), 256, 0, stream>>>(W1, W1T, 1024, 4096);
  cast_transpose    <<<dim3(32, 128), 256, 0, stream>>>(W2, W2T, 4096, 1024);
  pack_bias3        <<<12, 256, 0, stream>>>(bq, bk, bv, bqkv);

  // fused QKV, split-K=2: 1536 blocks, partials -> reduce(bias)+cast
  gemm_bt<<<dim3(24, 64), 256, 0, stream>>>(embB, WqkvT, nullptr, Qpart,
      1024, 1024, 1024, 3072, 1.0f, 0, 0, 3);
  reduce2_qkv<<<4096, 256, 0, stream>>>(Qpart, bqkv, QKVb);
  const uint16_t* Qb = QKVb;
  const uint16_t* Kb = QKVb + 1024;
  const uint16_t* Vb = QKVb + 2048;
  transpose_u16<<<dim3(32, 128), 256, 0, stream>>>(Vb, Vt, 4096, 1024, 3072);

  // exp(S) = exp(QK^T/sqrt(D)), lower-triangle blocks, bf16 direct
  gemm_bt<<<528, 256, 0, stream>>>(Qb, Kb, nullptr, Sb,
      1024, 3072, 3072, 4096, 0.03125f, 1, 0, 1);
  rowsum_exp<<<4096, 256, 0, stream>>>(Sb, lvec);
  // O' = exp(S) @ V (unnormalized), causal split-K=2 -> partials
  gemm_bt_n64<<<dim3(16, 64), 256, 0, stream>>>(Sb, Vt, nullptr, Opart,
      4096, 4096, 4096, 1024, 1.0f, 0, 0, 2);

  // reduce O partials, /l, + residual, LayerNorm -> xB
  add_layernorm<<<4096, 256, 0, stream>>>(Opart, lvec, emb, gamma, beta, xB);
  gemm_bt<<<dim3(32, 32), 256, 0, stream>>>(xB, W1T, b1, hB,
      1024, 1024, 1024, 4096, 1.0f, 1, 1, 0);
  // FFN2 split-K=2: 1024 blocks -> partials -> reduce(bias) -> d_out
  gemm_bt_n64<<<dim3(16, 64), 256, 0, stream>>>(hB, W2T, nullptr, Fpart,
      4096, 4096, 4096, 1024, 1.0f, 0, 0, 3);
  reduce2_bias<<<4096, 256, 0, stream>>>(Fpart, b2, (float*)d_out);
}

// Round 5
// 366.317 us; speedup vs baseline: 1.4395x; 1.1243x over previous
//
#include <hip/hip_runtime.h>
#include <stdint.h>

// Round 5: (a) QKV back to direct gemm (768 blocks, bias fused, bf16 out) —
// split-K's 200MB fp32 partial round-trip cost more than the occupancy won.
// (b) S-gemm re-tiled to BM=64 x BN=128 causal (1056 blocks, 4.1/CU) for
// occupancy. BK=64 + XOR swizzle + bf16 exp-S retained. O/FFN2 keep
// split-K=2 (partials only 32MB). Workspace requirement: 159 MB.

using short8 = __attribute__((ext_vector_type(8))) short;
using f32x4  = __attribute__((ext_vector_type(4))) float;

__device__ __forceinline__ uint16_t f2bf(float f) {
  uint32_t u = __builtin_bit_cast(uint32_t, f);
  u += 0x7FFFu + ((u >> 16) & 1u);        // RNE, inputs are finite
  return (uint16_t)(u >> 16);
}

__device__ __forceinline__ void gload_lds16(const uint16_t* g, uint16_t* l) {
  __builtin_amdgcn_global_load_lds(
      (__attribute__((address_space(1))) void*)(void*)g,
      (__attribute__((address_space(3))) void*)l, 16, 0, 0);
}

// LDS swizzle (BK=64): 16B slot s holds global chunk-col (s&7)^((s>>3)&7) of
// row s>>3. Read (row r, chunk cc) -> slot r*8 + (cc ^ (r&7)).

// ---------------- GEMM 128x128: C = scale*A@Bt^T + bias ---------------------
// mode 0: 2-D grid. mode 3: split-K=2, fp32 partials at half*4096*ldc.
__global__ __launch_bounds__(256) void gemm_bt(
    const uint16_t* __restrict__ A, const uint16_t* __restrict__ Bt,
    const float* __restrict__ bias, void* __restrict__ Cout,
    int K, int lda, int ldb, int ldc,
    float scale, int out_bf16, int relu, int mode)
{
  constexpr int BK = 64;
  __shared__ uint16_t As[128 * BK];
  __shared__ uint16_t Bs[128 * BK];
  int bm, bn, half = 0, klo = 0, khi = K;
  if (mode == 3) {
    bn = blockIdx.x; bm = blockIdx.y >> 1; half = blockIdx.y & 1;
    int mid = K >> 1; klo = half ? mid : 0; khi = half ? K : mid;
  } else {
    bm = blockIdx.y; bn = blockIdx.x;
  }

  int tid  = threadIdx.x;
  int lane = tid & 63;
  int wave = tid >> 6;
  int wm = (wave >> 1) * 64, wn = (wave & 1) * 64;
  int lr = lane & 15, quad = lane >> 4;

  // staging: 1024 16B-chunks per matrix, 4 per thread, source-side swizzle
  const uint16_t *Ag[4], *Bg[4];
  uint16_t *Al[4], *Bl[4];
#pragma unroll
  for (int s = 0; s < 4; ++s) {
    int c = tid + 256 * s;
    int r = c >> 3, q = (c & 7) ^ (r & 7);
    Ag[s] = A  + (size_t)(bm * 128 + r) * lda + q * 8;
    Bg[s] = Bt + (size_t)(bn * 128 + r) * ldb + q * 8;
    Al[s] = As + c * 8;
    Bl[s] = Bs + c * 8;
  }

  f32x4 acc[4][4] = {};

  for (int k0 = klo; k0 < khi; k0 += BK) {
    __syncthreads();
#pragma unroll
    for (int s = 0; s < 4; ++s) gload_lds16(Ag[s] + k0, Al[s]);
#pragma unroll
    for (int s = 0; s < 4; ++s) gload_lds16(Bg[s] + k0, Bl[s]);
    __syncthreads();
#pragma unroll
    for (int h = 0; h < 2; ++h) {
      short8 af[4], bfr[4];
      int cc = quad + 4 * h;
#pragma unroll
      for (int i = 0; i < 4; ++i) {
        int r = wm + i * 16 + lr;
        af[i] = *(const short8*)(&As[(r * 8 + (cc ^ (r & 7))) * 8]);
      }
#pragma unroll
      for (int j = 0; j < 4; ++j) {
        int r = wn + j * 16 + lr;
        bfr[j] = *(const short8*)(&Bs[(r * 8 + (cc ^ (r & 7))) * 8]);
      }
#pragma unroll
      for (int i = 0; i < 4; ++i)
#pragma unroll
        for (int j = 0; j < 4; ++j)
          acc[i][j] = __builtin_amdgcn_mfma_f32_16x16x32_bf16(af[i], bfr[j], acc[i][j], 0, 0, 0);
    }
  }

  void* Cw = (mode == 3) ? (void*)((float*)Cout + (size_t)half * 4096 * ldc) : Cout;
  int row0 = bm * 128 + wm + quad * 4;
  int col0 = bn * 128 + wn + lr;
#pragma unroll
  for (int j = 0; j < 4; ++j) {
    int col = col0 + j * 16;
    float bv = bias ? bias[col] : 0.0f;
#pragma unroll
    for (int i = 0; i < 4; ++i) {
#pragma unroll
      for (int r = 0; r < 4; ++r) {
        int row = row0 + i * 16 + r;
        float v = acc[i][j][r] * scale + bv;
        if (relu) v = fmaxf(v, 0.0f);
        size_t idx = (size_t)row * ldc + col;
        if (out_bf16) ((uint16_t*)Cw)[idx] = f2bf(v);
        else          ((float*)Cw)[idx]    = v;
      }
    }
  }
}

// ---------------- causal S-gemm, 64x128 tiles: Sb = exp(scale*Q@K^T) --------
// 1-D grid of 1056 lower-triangle tiles. cum(2m)=m(m+1), cum(2m+1)=(m+1)^2.
__global__ __launch_bounds__(256) void gemm_s(
    const uint16_t* __restrict__ Qm, const uint16_t* __restrict__ Km,
    uint16_t* __restrict__ Sb, int lda, int ldb, int ldc, float scale)
{
  constexpr int BK = 64;
  __shared__ uint16_t As[64 * BK];
  __shared__ uint16_t Bs[128 * BK];
  int t = blockIdx.x;
  int u = (int)sqrtf((float)t);
  while ((u + 1) * (u + 1) <= t) ++u;
  while (u * u > t) --u;
  int i64, bn;
  if (t < u * (u + 1)) { i64 = 2 * u - 1; bn = t - u * u; }
  else                 { i64 = 2 * u;     bn = t - u * (u + 1); }

  int tid  = threadIdx.x;
  int lane = tid & 63;
  int wave = tid >> 6;
  int wm = (wave >> 1) * 32, wn = (wave & 1) * 64;   // wave: 32 rows x 64 cols
  int lr = lane & 15, quad = lane >> 4;

  // A: 512 chunks (2/thread), B: 1024 chunks (4/thread)
  const uint16_t *Ag[2], *Bg[4];
  uint16_t *Al[2], *Bl[4];
#pragma unroll
  for (int s = 0; s < 2; ++s) {
    int c = tid + 256 * s;
    int r = c >> 3, q = (c & 7) ^ (r & 7);
    Ag[s] = Qm + (size_t)(i64 * 64 + r) * lda + q * 8;
    Al[s] = As + c * 8;
  }
#pragma unroll
  for (int s = 0; s < 4; ++s) {
    int c = tid + 256 * s;
    int r = c >> 3, q = (c & 7) ^ (r & 7);
    Bg[s] = Km + (size_t)(bn * 128 + r) * ldb + q * 8;
    Bl[s] = Bs + c * 8;
  }

  f32x4 acc[2][4] = {};

  for (int k0 = 0; k0 < 1024; k0 += BK) {
    __syncthreads();
#pragma unroll
    for (int s = 0; s < 2; ++s) gload_lds16(Ag[s] + k0, Al[s]);
#pragma unroll
    for (int s = 0; s < 4; ++s) gload_lds16(Bg[s] + k0, Bl[s]);
    __syncthreads();
#pragma unroll
    for (int h = 0; h < 2; ++h) {
      short8 af[2], bfr[4];
      int cc = quad + 4 * h;
#pragma unroll
      for (int i = 0; i < 2; ++i) {
        int r = wm + i * 16 + lr;
        af[i] = *(const short8*)(&As[(r * 8 + (cc ^ (r & 7))) * 8]);
      }
#pragma unroll
      for (int j = 0; j < 4; ++j) {
        int r = wn + j * 16 + lr;
        bfr[j] = *(const short8*)(&Bs[(r * 8 + (cc ^ (r & 7))) * 8]);
      }
#pragma unroll
      for (int i = 0; i < 2; ++i)
#pragma unroll
        for (int j = 0; j < 4; ++j)
          acc[i][j] = __builtin_amdgcn_mfma_f32_16x16x32_bf16(af[i], bfr[j], acc[i][j], 0, 0, 0);
    }
  }

  int row0 = i64 * 64 + wm + quad * 4;
  int col0 = bn * 128 + wn + lr;
#pragma unroll
  for (int j = 0; j < 4; ++j) {
    int col = col0 + j * 16;
#pragma unroll
    for (int i = 0; i < 2; ++i) {
#pragma unroll
      for (int r = 0; r < 4; ++r) {
        int row = row0 + i * 16 + r;
        float v = (col <= row) ? __expf(acc[i][j][r] * scale) : 0.0f;
        Sb[(size_t)row * ldc + col] = f2bf(v);
      }
    }
  }
}

// ---------------- GEMM 128x64 (N=1024 outputs) ------------------------------
// mode 2: split-K=2 causal-O (grid y=64). mode 3: split-K=2 full.
// Split modes write fp32 partials at half*4096*ldc (no bias/relu/scale!=1).
__global__ __launch_bounds__(256) void gemm_bt_n64(
    const uint16_t* __restrict__ A, const uint16_t* __restrict__ Bt,
    const float* __restrict__ bias, void* __restrict__ Cout,
    int K, int lda, int ldb, int ldc,
    float scale, int out_bf16, int relu, int mode)
{
  constexpr int BK = 64;
  __shared__ uint16_t As[128 * BK];
  __shared__ uint16_t Bs[64 * BK];
  int bn = blockIdx.x, b = blockIdx.y;
  int bm, half = 0, klo = 0, khi = K;
  if (mode == 2) {
    int t = b >> 1; half = b & 1;
    bm = (t & 1) ? (t >> 1) : (31 - (t >> 1));       // long bm's early
    int kmax = (bm + 1) << 7, mid = kmax >> 1;       // mid multiple of 64
    klo = half ? mid : 0; khi = half ? kmax : mid;
  } else if (mode == 3) {
    bm = b >> 1; half = b & 1;
    int mid = K >> 1; klo = half ? mid : 0; khi = half ? K : mid;
  } else {
    bm = b;
  }

  int tid  = threadIdx.x;
  int lane = tid & 63;
  int wave = tid >> 6;
  int wm = (wave & 1) * 64, wn = (wave >> 1) * 32;   // wave: 64 rows x 32 cols
  int lr = lane & 15, quad = lane >> 4;

  const uint16_t *Ag[4], *Bg[2];
  uint16_t *Al[4], *Bl[2];
#pragma unroll
  for (int s = 0; s < 4; ++s) {
    int c = tid + 256 * s;
    int r = c >> 3, q = (c & 7) ^ (r & 7);
    Ag[s] = A + (size_t)(bm * 128 + r) * lda + q * 8;
    Al[s] = As + c * 8;
  }
#pragma unroll
  for (int s = 0; s < 2; ++s) {
    int c = tid + 256 * s;
    int r = c >> 3, q = (c & 7) ^ (r & 7);
    Bg[s] = Bt + (size_t)(bn * 64 + r) * ldb + q * 8;
    Bl[s] = Bs + c * 8;
  }

  f32x4 acc[4][2] = {};

  for (int k0 = klo; k0 < khi; k0 += BK) {
    __syncthreads();
#pragma unroll
    for (int s = 0; s < 4; ++s) gload_lds16(Ag[s] + k0, Al[s]);
#pragma unroll
    for (int s = 0; s < 2; ++s) gload_lds16(Bg[s] + k0, Bl[s]);
    __syncthreads();
#pragma unroll
    for (int h = 0; h < 2; ++h) {
      short8 af[4], bfr[2];
      int cc = quad + 4 * h;
#pragma unroll
      for (int i = 0; i < 4; ++i) {
        int r = wm + i * 16 + lr;
        af[i] = *(const short8*)(&As[(r * 8 + (cc ^ (r & 7))) * 8]);
      }
#pragma unroll
      for (int j = 0; j < 2; ++j) {
        int r = wn + j * 16 + lr;
        bfr[j] = *(const short8*)(&Bs[(r * 8 + (cc ^ (r & 7))) * 8]);
      }
#pragma unroll
      for (int i = 0; i < 4; ++i)
#pragma unroll
        for (int j = 0; j < 2; ++j)
          acc[i][j] = __builtin_amdgcn_mfma_f32_16x16x32_bf16(af[i], bfr[j], acc[i][j], 0, 0, 0);
    }
  }

  void* Cw = (mode >= 2) ? (void*)((float*)Cout + (size_t)half * 4096 * ldc) : Cout;
  int row0 = bm * 128 + wm + quad * 4;
  int col0 = bn * 64 + wn + lr;
#pragma unroll
  for (int j = 0; j < 2; ++j) {
    int col = col0 + j * 16;
    float bv = bias ? bias[col] : 0.0f;
#pragma unroll
    for (int i = 0; i < 4; ++i) {
#pragma unroll
      for (int r = 0; r < 4; ++r) {
        int row = row0 + i * 16 + r;
        float v = acc[i][j][r] * scale + bv;
        if (relu) v = fmaxf(v, 0.0f);
        size_t idx = (size_t)row * ldc + col;
        if (out_bf16) ((uint16_t*)Cw)[idx] = f2bf(v);
        else          ((float*)Cw)[idx]    = v;
      }
    }
  }
}

// ---------------- reductions ------------------------------------------------
__device__ __forceinline__ float block_sum(float v, float* red) {
#pragma unroll
  for (int o = 32; o > 0; o >>= 1) v += __shfl_xor(v, o, 64);
  if ((threadIdx.x & 63) == 0) red[threadIdx.x >> 6] = v;
  __syncthreads();
  v = red[0] + red[1] + red[2] + red[3];
  __syncthreads();
  return v;
}

// ---------------- row sums of exp-S (softmax denominators) ------------------
__global__ __launch_bounds__(256) void rowsum_exp(
    const uint16_t* __restrict__ Sb, float* __restrict__ l)
{
  __shared__ float red[4];
  int i = blockIdx.x, tid = threadIdx.x;
  const ushort4* row = (const ushort4*)(Sb + (size_t)i * 4096);
  int lim4 = (((i >> 7) + 1) << 7) >> 2;     // valid cols / 4 (zeros beyond i)
  float s = 0.0f;
  for (int c = tid; c < lim4; c += 256) {
    ushort4 u = row[c];
    s += __builtin_bit_cast(float, (uint32_t)u.x << 16)
       + __builtin_bit_cast(float, (uint32_t)u.y << 16)
       + __builtin_bit_cast(float, (uint32_t)u.z << 16)
       + __builtin_bit_cast(float, (uint32_t)u.w << 16);
  }
  s = block_sum(s, red);
  if (tid == 0) l[i] = s;
}

// ---------------- O-partials reduce /l + residual + LayerNorm -> bf16 -------
__global__ __launch_bounds__(256) void add_layernorm(
    const float* __restrict__ P, const float* __restrict__ l,
    const float* __restrict__ emb, const float* __restrict__ gamma,
    const float* __restrict__ beta, uint16_t* __restrict__ xB)
{
  __shared__ float red[4];
  int i = blockIdx.x, tid = threadIdx.x;
  float inv_l = 1.0f / l[i];
  float4 a0 = ((const float4*)(P + (size_t)i * 1024))[tid];
  float4 a1 = ((const float4*)(P + 4194304 + (size_t)i * 1024))[tid];
  float4 b  = ((const float4*)(emb + (size_t)i * 1024))[tid];
  float x0 = (a0.x + a1.x) * inv_l + b.x, x1 = (a0.y + a1.y) * inv_l + b.y;
  float x2 = (a0.z + a1.z) * inv_l + b.z, x3 = (a0.w + a1.w) * inv_l + b.w;
  float mu = block_sum(x0 + x1 + x2 + x3, red) * (1.0f / 1024.0f);
  float d0 = x0 - mu, d1 = x1 - mu, d2 = x2 - mu, d3 = x3 - mu;
  float var = block_sum(d0 * d0 + d1 * d1 + d2 * d2 + d3 * d3, red) * (1.0f / 1024.0f);
  float rs = rsqrtf(var + 1e-5f);
  float4 g  = ((const float4*)gamma)[tid];
  float4 be = ((const float4*)beta)[tid];
  ushort4 o;
  o.x = f2bf(d0 * rs * g.x + be.x);
  o.y = f2bf(d1 * rs * g.y + be.y);
  o.z = f2bf(d2 * rs * g.z + be.z);
  o.w = f2bf(d3 * rs * g.w + be.w);
  ((ushort4*)(xB + (size_t)i * 1024))[tid] = o;
}

// ---------------- FFN2-partials reduce + bias -> fp32 d_out -----------------
__global__ __launch_bounds__(256) void reduce2_bias(
    const float* __restrict__ P, const float* __restrict__ bias,
    float* __restrict__ out)
{
  int i = blockIdx.x, tid = threadIdx.x;
  float4 a = ((const float4*)(P + (size_t)i * 1024))[tid];
  float4 c = ((const float4*)(P + 4194304 + (size_t)i * 1024))[tid];
  float4 bv = ((const float4*)bias)[tid];
  float4 o;
  o.x = a.x + c.x + bv.x; o.y = a.y + c.y + bv.y;
  o.z = a.z + c.z + bv.z; o.w = a.w + c.w + bv.w;
  ((float4*)(out + (size_t)i * 1024))[tid] = o;
}

// ---------------- casts / transposes / bias pack ----------------------------
__global__ __launch_bounds__(256) void cast_f32_bf16(
    const float* __restrict__ in, uint16_t* __restrict__ out, int n4)
{
  int idx = blockIdx.x * 256 + threadIdx.x;
  if (idx >= n4) return;
  float4 v = ((const float4*)in)[idx];
  ushort4 o; o.x = f2bf(v.x); o.y = f2bf(v.y); o.z = f2bf(v.z); o.w = f2bf(v.w);
  ((ushort4*)out)[idx] = o;
}

__global__ __launch_bounds__(256) void cast_transpose(
    const float* __restrict__ in, uint16_t* __restrict__ out, int R, int C)
{
  __shared__ float tile[32][33];
  int tx = threadIdx.x & 31, ty = threadIdx.x >> 5;
  int r0 = blockIdx.y * 32, c0 = blockIdx.x * 32;
#pragma unroll
  for (int r = 0; r < 32; r += 8)
    tile[ty + r][tx] = in[(size_t)(r0 + ty + r) * C + c0 + tx];
  __syncthreads();
#pragma unroll
  for (int r = 0; r < 32; r += 8)
    out[(size_t)(c0 + ty + r) * R + r0 + tx] = f2bf(tile[tx][ty + r]);
}

// three 1024x1024 weight transposes in one launch (z = which matrix)
__global__ __launch_bounds__(256) void cast_transpose_qkv(
    const float* __restrict__ Wq, const float* __restrict__ Wk,
    const float* __restrict__ Wv, uint16_t* __restrict__ out)
{
  __shared__ float tile[32][33];
  const float* in = (blockIdx.z == 0) ? Wq : (blockIdx.z == 1) ? Wk : Wv;
  uint16_t* o = out + (size_t)blockIdx.z * 1048576;
  int tx = threadIdx.x & 31, ty = threadIdx.x >> 5;
  int r0 = blockIdx.y * 32, c0 = blockIdx.x * 32;
#pragma unroll
  for (int r = 0; r < 32; r += 8)
    tile[ty + r][tx] = in[(size_t)(r0 + ty + r) * 1024 + c0 + tx];
  __syncthreads();
#pragma unroll
  for (int r = 0; r < 32; r += 8)
    o[(size_t)(c0 + ty + r) * 1024 + r0 + tx] = f2bf(tile[tx][ty + r]);
}

// bf16 [R,C] (row stride ldin) -> bf16 [C,R]
__global__ __launch_bounds__(256) void transpose_u16(
    const uint16_t* __restrict__ in, uint16_t* __restrict__ out, int R, int C, int ldin)
{
  __shared__ uint16_t tile[32][33];
  int tx = threadIdx.x & 31, ty = threadIdx.x >> 5;
  int r0 = blockIdx.y * 32, c0 = blockIdx.x * 32;
#pragma unroll
  for (int r = 0; r < 32; r += 8)
    tile[ty + r][tx] = in[(size_t)(r0 + ty + r) * ldin + c0 + tx];
  __syncthreads();
#pragma unroll
  for (int r = 0; r < 32; r += 8)
    out[(size_t)(c0 + ty + r) * R + r0 + tx] = tile[tx][ty + r];
}

__global__ __launch_bounds__(256) void pack_bias3(
    const float* __restrict__ b0, const float* __restrict__ b1,
    const float* __restrict__ b2, float* __restrict__ out)
{
  int i = blockIdx.x * 256 + threadIdx.x;   // 3072 threads
  float v = (i < 1024) ? b0[i] : (i < 2048) ? b1[i - 1024] : b2[i - 2048];
  out[i] = v;
}

// ---------------- launcher --------------------------------------------------
extern "C" void kernel_launch(void* const* d_in, const int* in_sizes, int n_in,
                              void* d_out, int out_size, void* d_ws, size_t ws_size,
                              hipStream_t stream) {
  const float* emb   = (const float*)d_in[0];
  const float* Wq    = (const float*)d_in[1];
  const float* bq    = (const float*)d_in[2];
  const float* Wk    = (const float*)d_in[3];
  const float* bk    = (const float*)d_in[4];
  const float* Wv    = (const float*)d_in[5];
  const float* bv    = (const float*)d_in[6];
  const float* gamma = (const float*)d_in[7];
  const float* beta  = (const float*)d_in[8];
  const float* W1    = (const float*)d_in[9];
  const float* b1    = (const float*)d_in[10];
  const float* W2    = (const float*)d_in[11];
  const float* b2    = (const float*)d_in[12];

  char* w = (char*)d_ws;
  const size_t MB = 1ull << 20;
  uint16_t* embB  = (uint16_t*)(w + 0 * MB);    // [4096,1024] bf16
  uint16_t* WqkvT = (uint16_t*)(w + 8 * MB);    // [3072,1024] packed q|k|v
  uint16_t* W1T   = (uint16_t*)(w + 14 * MB);   // [4096,1024]
  uint16_t* W2T   = (uint16_t*)(w + 22 * MB);   // [1024,4096]
  float*    bqkv  = (float*)(w + 30 * MB);      // [3072]
  float*    lvec  = (float*)(w + 30 * MB + 65536); // [4096] softmax denominators
  uint16_t* QKVb  = (uint16_t*)(w + 31 * MB);   // [4096,3072]
  uint16_t* Vt    = (uint16_t*)(w + 55 * MB);   // [1024,4096]
  uint16_t* xB    = (uint16_t*)(w + 0 * MB);    // reuses embB (dead after QKV)
  uint16_t* hB    = (uint16_t*)(w + 63 * MB);   // [4096,4096] bf16
  uint16_t* Sb    = (uint16_t*)(w + 95 * MB);   // [4096,4096] bf16 exp(S)
  float*    Opart = (float*)(w + 63 * MB);      // [2][4096,1024] fp32 (pre-FFN1)
  float*    Fpart = (float*)(w + 127 * MB);     // [2][4096,1024] fp32
  // total ws requirement: 159 MB

  cast_f32_bf16     <<<4096, 256, 0, stream>>>(emb, embB, 1024 * 1024);
  cast_transpose_qkv<<<dim3(32, 32, 3), 256, 0, stream>>>(Wq, Wk, Wv, WqkvT);
  cast_transpose    <<<dim3(128, 32), 256, 0, stream>>>(W1, W1T, 1024, 4096);
  cast_transpose    <<<dim3(32, 128), 256, 0, stream>>>(W2, W2T, 4096, 1024);
  pack_bias3        <<<12, 256, 0, stream>>>(bq, bk, bv, bqkv);

  // fused QKV, direct: 768 blocks (3/CU), bias fused, bf16 out
  gemm_bt<<<dim3(24, 32), 256, 0, stream>>>(embB, WqkvT, bqkv, QKVb,
      1024, 1024, 1024, 3072, 1.0f, 1, 0, 0);
  const uint16_t* Qb = QKVb;
  const uint16_t* Kb = QKVb + 1024;
  const uint16_t* Vb = QKVb + 2048;
  transpose_u16<<<dim3(32, 128), 256, 0, stream>>>(Vb, Vt, 4096, 1024, 3072);

  // exp(S) = exp(QK^T/sqrt(D)), 64x128 causal tiles, bf16 direct
  gemm_s<<<1056, 256, 0, stream>>>(Qb, Kb, Sb, 3072, 3072, 4096, 0.03125f);
  rowsum_exp<<<4096, 256, 0, stream>>>(Sb, lvec);
  // O' = exp(S) @ V (unnormalized), causal split-K=2 -> partials
  gemm_bt_n64<<<dim3(16, 64), 256, 0, stream>>>(Sb, Vt, nullptr, Opart,
      4096, 4096, 4096, 1024, 1.0f, 0, 0, 2);

  // reduce O partials, /l, + residual, LayerNorm -> xB
  add_layernorm<<<4096, 256, 0, stream>>>(Opart, lvec, emb, gamma, beta, xB);
  gemm_bt<<<dim3(32, 32), 256, 0, stream>>>(xB, W1T, b1, hB,
      1024, 1024, 1024, 4096, 1.0f, 1, 1, 0);
  // FFN2 split-K=2: 1024 blocks -> partials -> reduce(bias) -> d_out
  gemm_bt_n64<<<dim3(16, 64), 256, 0, stream>>>(hB, W2T, nullptr, Fpart,
      4096, 4096, 4096, 1024, 1.0f, 0, 0, 3);
  reduce2_bias<<<4096, 256, 0, stream>>>(Fpart, b2, (float*)d_out);
}

// Round 6
// 364.012 us; speedup vs baseline: 1.4486x; 1.0063x over previous
//
#include <hip/hip_runtime.h>
#include <stdint.h>

// Round 6: pipeline compaction. 14 -> 7 dispatches:
//   prep (all casts/transposes/bias-pack + lvec=0 + d_out=b2) ->
//   QKV gemm (writes Q,K normally; V written TRANSPOSED to Vt in-epilogue) ->
//   gemm_s (exp-S bf16 + fused atomic row-sums into lvec) ->
//   O-gemm (split-K=2 partials) -> add_layernorm (reduce+/l+LN) ->
//   FFN1 -> FFN2 (split-K=2, epilogue atomicAdd into bias-initialized d_out).
// BK=64, XOR-swizzled LDS (conflict-free), shift-free softmax retained.
// Workspace requirement: 159 MB.

using short8 = __attribute__((ext_vector_type(8))) short;
using f32x4  = __attribute__((ext_vector_type(4))) float;

__device__ __forceinline__ uint16_t f2bf(float f) {
  uint32_t u = __builtin_bit_cast(uint32_t, f);
  u += 0x7FFFu + ((u >> 16) & 1u);        // RNE, inputs are finite
  return (uint16_t)(u >> 16);
}

__device__ __forceinline__ void gload_lds16(const uint16_t* g, uint16_t* l) {
  __builtin_amdgcn_global_load_lds(
      (__attribute__((address_space(1))) void*)(void*)g,
      (__attribute__((address_space(3))) void*)l, 16, 0, 0);
}

// LDS swizzle (BK=64): 16B slot s holds global chunk-col (s&7)^((s>>3)&7) of
// row s>>3. Read (row r, chunk cc) -> slot r*8 + (cc ^ (r&7)).

// ---------------- GEMM 128x128: C = scale*A@Bt^T + bias ---------------------
// mode 0: 2-D grid. VtOut!=nullptr: cols>=2048 (V region) are written
// transposed to VtOut[col-2048][row] instead of C.
__global__ __launch_bounds__(256) void gemm_bt(
    const uint16_t* __restrict__ A, const uint16_t* __restrict__ Bt,
    const float* __restrict__ bias, void* __restrict__ Cout,
    uint16_t* __restrict__ VtOut,
    int K, int lda, int ldb, int ldc,
    float scale, int out_bf16, int relu)
{
  constexpr int BK = 64;
  __shared__ uint16_t As[128 * BK];
  __shared__ uint16_t Bs[128 * BK];
  int bm = blockIdx.y, bn = blockIdx.x;

  int tid  = threadIdx.x;
  int lane = tid & 63;
  int wave = tid >> 6;
  int wm = (wave >> 1) * 64, wn = (wave & 1) * 64;
  int lr = lane & 15, quad = lane >> 4;

  const uint16_t *Ag[4], *Bg[4];
  uint16_t *Al[4], *Bl[4];
#pragma unroll
  for (int s = 0; s < 4; ++s) {
    int c = tid + 256 * s;
    int r = c >> 3, q = (c & 7) ^ (r & 7);
    Ag[s] = A  + (size_t)(bm * 128 + r) * lda + q * 8;
    Bg[s] = Bt + (size_t)(bn * 128 + r) * ldb + q * 8;
    Al[s] = As + c * 8;
    Bl[s] = Bs + c * 8;
  }

  f32x4 acc[4][4] = {};

  for (int k0 = 0; k0 < K; k0 += BK) {
    __syncthreads();
#pragma unroll
    for (int s = 0; s < 4; ++s) gload_lds16(Ag[s] + k0, Al[s]);
#pragma unroll
    for (int s = 0; s < 4; ++s) gload_lds16(Bg[s] + k0, Bl[s]);
    __syncthreads();
#pragma unroll
    for (int h = 0; h < 2; ++h) {
      short8 af[4], bfr[4];
      int cc = quad + 4 * h;
#pragma unroll
      for (int i = 0; i < 4; ++i) {
        int r = wm + i * 16 + lr;
        af[i] = *(const short8*)(&As[(r * 8 + (cc ^ (r & 7))) * 8]);
      }
#pragma unroll
      for (int j = 0; j < 4; ++j) {
        int r = wn + j * 16 + lr;
        bfr[j] = *(const short8*)(&Bs[(r * 8 + (cc ^ (r & 7))) * 8]);
      }
#pragma unroll
      for (int i = 0; i < 4; ++i)
#pragma unroll
        for (int j = 0; j < 4; ++j)
          acc[i][j] = __builtin_amdgcn_mfma_f32_16x16x32_bf16(af[i], bfr[j], acc[i][j], 0, 0, 0);
    }
  }

  int row0 = bm * 128 + wm + quad * 4;
  int col0 = bn * 128 + wn + lr;
#pragma unroll
  for (int j = 0; j < 4; ++j) {
    int col = col0 + j * 16;
    float bv = bias ? bias[col] : 0.0f;
#pragma unroll
    for (int i = 0; i < 4; ++i) {
#pragma unroll
      for (int r = 0; r < 4; ++r) {
        int row = row0 + i * 16 + r;
        float v = acc[i][j][r] * scale + bv;
        if (relu) v = fmaxf(v, 0.0f);
        if (VtOut && col >= 2048) {
          VtOut[(size_t)(col - 2048) * 4096 + row] = f2bf(v);   // V transposed
        } else {
          size_t idx = (size_t)row * ldc + col;
          if (out_bf16) ((uint16_t*)Cout)[idx] = f2bf(v);
          else          ((float*)Cout)[idx]    = v;
        }
      }
    }
  }
}

// ---------------- causal S-gemm, 64x128 tiles: Sb = exp(scale*Q@K^T) --------
// 1-D grid of 1056 lower-triangle tiles; fused row-sum atomics into lvec
// (lvec zero-initialized by prep). cum(2m)=m(m+1), cum(2m+1)=(m+1)^2.
__global__ __launch_bounds__(256) void gemm_s(
    const uint16_t* __restrict__ Qm, const uint16_t* __restrict__ Km,
    uint16_t* __restrict__ Sb, float* __restrict__ lvec,
    int lda, int ldb, int ldc, float scale)
{
  constexpr int BK = 64;
  __shared__ uint16_t As[64 * BK];
  __shared__ uint16_t Bs[128 * BK];
  int t = blockIdx.x;
  int u = (int)sqrtf((float)t);
  while ((u + 1) * (u + 1) <= t) ++u;
  while (u * u > t) --u;
  int i64, bn;
  if (t < u * (u + 1)) { i64 = 2 * u - 1; bn = t - u * u; }
  else                 { i64 = 2 * u;     bn = t - u * (u + 1); }

  int tid  = threadIdx.x;
  int lane = tid & 63;
  int wave = tid >> 6;
  int wm = (wave >> 1) * 32, wn = (wave & 1) * 64;   // wave: 32 rows x 64 cols
  int lr = lane & 15, quad = lane >> 4;

  const uint16_t *Ag[2], *Bg[4];
  uint16_t *Al[2], *Bl[4];
#pragma unroll
  for (int s = 0; s < 2; ++s) {
    int c = tid + 256 * s;
    int r = c >> 3, q = (c & 7) ^ (r & 7);
    Ag[s] = Qm + (size_t)(i64 * 64 + r) * lda + q * 8;
    Al[s] = As + c * 8;
  }
#pragma unroll
  for (int s = 0; s < 4; ++s) {
    int c = tid + 256 * s;
    int r = c >> 3, q = (c & 7) ^ (r & 7);
    Bg[s] = Km + (size_t)(bn * 128 + r) * ldb + q * 8;
    Bl[s] = Bs + c * 8;
  }

  f32x4 acc[2][4] = {};

  for (int k0 = 0; k0 < 1024; k0 += BK) {
    __syncthreads();
#pragma unroll
    for (int s = 0; s < 2; ++s) gload_lds16(Ag[s] + k0, Al[s]);
#pragma unroll
    for (int s = 0; s < 4; ++s) gload_lds16(Bg[s] + k0, Bl[s]);
    __syncthreads();
#pragma unroll
    for (int h = 0; h < 2; ++h) {
      short8 af[2], bfr[4];
      int cc = quad + 4 * h;
#pragma unroll
      for (int i = 0; i < 2; ++i) {
        int r = wm + i * 16 + lr;
        af[i] = *(const short8*)(&As[(r * 8 + (cc ^ (r & 7))) * 8]);
      }
#pragma unroll
      for (int j = 0; j < 4; ++j) {
        int r = wn + j * 16 + lr;
        bfr[j] = *(const short8*)(&Bs[(r * 8 + (cc ^ (r & 7))) * 8]);
      }
#pragma unroll
      for (int i = 0; i < 2; ++i)
#pragma unroll
        for (int j = 0; j < 4; ++j)
          acc[i][j] = __builtin_amdgcn_mfma_f32_16x16x32_bf16(af[i], bfr[j], acc[i][j], 0, 0, 0);
    }
  }

  int row0 = i64 * 64 + wm + quad * 4;
  int col0 = bn * 128 + wn + lr;
#pragma unroll
  for (int i = 0; i < 2; ++i) {
#pragma unroll
    for (int r = 0; r < 4; ++r) {
      int row = row0 + i * 16 + r;
      float s = 0.0f;
#pragma unroll
      for (int j = 0; j < 4; ++j) {
        int col = col0 + j * 16;
        float v = (col <= row) ? __expf(acc[i][j][r] * scale) : 0.0f;
        Sb[(size_t)row * ldc + col] = f2bf(v);
        s += v;
      }
      // reduce across the 16 lanes holding this row's columns
#pragma unroll
      for (int o = 8; o > 0; o >>= 1) s += __shfl_xor(s, o, 64);
      if (lr == 0) unsafeAtomicAdd(&lvec[row], s);
    }
  }
}

// ---------------- GEMM 128x64 (N=1024 outputs) ------------------------------
// mode 2: split-K=2 causal-O (grid y=64), fp32 partials at half*4096*ldc.
// mode 4: split-K=2 full-K, epilogue unsafeAtomicAdd into fp32 Cout
//         (pre-initialized with bias by prep).
__global__ __launch_bounds__(256) void gemm_bt_n64(
    const uint16_t* __restrict__ A, const uint16_t* __restrict__ Bt,
    void* __restrict__ Cout,
    int K, int lda, int ldb, int ldc, int mode)
{
  constexpr int BK = 64;
  __shared__ uint16_t As[128 * BK];
  __shared__ uint16_t Bs[64 * BK];
  int bn = blockIdx.x, b = blockIdx.y;
  int bm, half = 0, klo = 0, khi = K;
  if (mode == 2) {
    int t = b >> 1; half = b & 1;
    bm = (t & 1) ? (t >> 1) : (31 - (t >> 1));       // long bm's early
    int kmax = (bm + 1) << 7, mid = kmax >> 1;       // mid multiple of 64
    klo = half ? mid : 0; khi = half ? kmax : mid;
  } else {
    bm = b >> 1; half = b & 1;
    int mid = K >> 1; klo = half ? mid : 0; khi = half ? K : mid;
  }

  int tid  = threadIdx.x;
  int lane = tid & 63;
  int wave = tid >> 6;
  int wm = (wave & 1) * 64, wn = (wave >> 1) * 32;   // wave: 64 rows x 32 cols
  int lr = lane & 15, quad = lane >> 4;

  const uint16_t *Ag[4], *Bg[2];
  uint16_t *Al[4], *Bl[2];
#pragma unroll
  for (int s = 0; s < 4; ++s) {
    int c = tid + 256 * s;
    int r = c >> 3, q = (c & 7) ^ (r & 7);
    Ag[s] = A + (size_t)(bm * 128 + r) * lda + q * 8;
    Al[s] = As + c * 8;
  }
#pragma unroll
  for (int s = 0; s < 2; ++s) {
    int c = tid + 256 * s;
    int r = c >> 3, q = (c & 7) ^ (r & 7);
    Bg[s] = Bt + (size_t)(bn * 64 + r) * ldb + q * 8;
    Bl[s] = Bs + c * 8;
  }

  f32x4 acc[4][2] = {};

  for (int k0 = klo; k0 < khi; k0 += BK) {
    __syncthreads();
#pragma unroll
    for (int s = 0; s < 4; ++s) gload_lds16(Ag[s] + k0, Al[s]);
#pragma unroll
    for (int s = 0; s < 2; ++s) gload_lds16(Bg[s] + k0, Bl[s]);
    __syncthreads();
#pragma unroll
    for (int h = 0; h < 2; ++h) {
      short8 af[4], bfr[2];
      int cc = quad + 4 * h;
#pragma unroll
      for (int i = 0; i < 4; ++i) {
        int r = wm + i * 16 + lr;
        af[i] = *(const short8*)(&As[(r * 8 + (cc ^ (r & 7))) * 8]);
      }
#pragma unroll
      for (int j = 0; j < 2; ++j) {
        int r = wn + j * 16 + lr;
        bfr[j] = *(const short8*)(&Bs[(r * 8 + (cc ^ (r & 7))) * 8]);
      }
#pragma unroll
      for (int i = 0; i < 4; ++i)
#pragma unroll
        for (int j = 0; j < 2; ++j)
          acc[i][j] = __builtin_amdgcn_mfma_f32_16x16x32_bf16(af[i], bfr[j], acc[i][j], 0, 0, 0);
    }
  }

  int row0 = bm * 128 + wm + quad * 4;
  int col0 = bn * 64 + wn + lr;
  if (mode == 4) {
    float* Cw = (float*)Cout;
#pragma unroll
    for (int j = 0; j < 2; ++j)
#pragma unroll
      for (int i = 0; i < 4; ++i)
#pragma unroll
        for (int r = 0; r < 4; ++r) {
          size_t idx = (size_t)(row0 + i * 16 + r) * ldc + col0 + j * 16;
          unsafeAtomicAdd(&Cw[idx], acc[i][j][r]);
        }
  } else {
    float* Cw = (float*)Cout + (size_t)half * 4096 * ldc;
#pragma unroll
    for (int j = 0; j < 2; ++j)
#pragma unroll
      for (int i = 0; i < 4; ++i)
#pragma unroll
        for (int r = 0; r < 4; ++r) {
          size_t idx = (size_t)(row0 + i * 16 + r) * ldc + col0 + j * 16;
          Cw[idx] = acc[i][j][r];
        }
  }
}

// ---------------- reductions ------------------------------------------------
__device__ __forceinline__ float block_sum(float v, float* red) {
#pragma unroll
  for (int o = 32; o > 0; o >>= 1) v += __shfl_xor(v, o, 64);
  if ((threadIdx.x & 63) == 0) red[threadIdx.x >> 6] = v;
  __syncthreads();
  v = red[0] + red[1] + red[2] + red[3];
  __syncthreads();
  return v;
}

// ---------------- O-partials reduce /l + residual + LayerNorm -> bf16 -------
__global__ __launch_bounds__(256) void add_layernorm(
    const float* __restrict__ P, const float* __restrict__ l,
    const float* __restrict__ emb, const float* __restrict__ gamma,
    const float* __restrict__ beta, uint16_t* __restrict__ xB)
{
  __shared__ float red[4];
  int i = blockIdx.x, tid = threadIdx.x;
  float inv_l = 1.0f / l[i];
  float4 a0 = ((const float4*)(P + (size_t)i * 1024))[tid];
  float4 a1 = ((const float4*)(P + 4194304 + (size_t)i * 1024))[tid];
  float4 b  = ((const float4*)(emb + (size_t)i * 1024))[tid];
  float x0 = (a0.x + a1.x) * inv_l + b.x, x1 = (a0.y + a1.y) * inv_l + b.y;
  float x2 = (a0.z + a1.z) * inv_l + b.z, x3 = (a0.w + a1.w) * inv_l + b.w;
  float mu = block_sum(x0 + x1 + x2 + x3, red) * (1.0f / 1024.0f);
  float d0 = x0 - mu, d1 = x1 - mu, d2 = x2 - mu, d3 = x3 - mu;
  float var = block_sum(d0 * d0 + d1 * d1 + d2 * d2 + d3 * d3, red) * (1.0f / 1024.0f);
  float rs = rsqrtf(var + 1e-5f);
  float4 g  = ((const float4*)gamma)[tid];
  float4 be = ((const float4*)beta)[tid];
  ushort4 o;
  o.x = f2bf(d0 * rs * g.x + be.x);
  o.y = f2bf(d1 * rs * g.y + be.y);
  o.z = f2bf(d2 * rs * g.z + be.z);
  o.w = f2bf(d3 * rs * g.w + be.w);
  ((ushort4*)(xB + (size_t)i * 1024))[tid] = o;
}

// ---------------- prep: all casts/transposes/bias/init in one launch --------
// blocks [0,4096): emb->bf16. [4096,7168): Wq/Wk/Wv cast-transpose.
// [7168,11264): W1T. [11264,15360): W2T. [15360,15372): bqkv pack.
// [15372]: lvec=0. [15373,19469): d_out rows = b2 (FFN2 atomic base).
__global__ __launch_bounds__(256) void prep(
    const float* __restrict__ emb, const float* __restrict__ Wq,
    const float* __restrict__ Wk, const float* __restrict__ Wv,
    const float* __restrict__ W1, const float* __restrict__ W2,
    const float* __restrict__ bq, const float* __restrict__ bk,
    const float* __restrict__ bv, const float* __restrict__ b2,
    uint16_t* __restrict__ embB, uint16_t* __restrict__ WqkvT,
    uint16_t* __restrict__ W1T, uint16_t* __restrict__ W2T,
    float* __restrict__ bqkv, float* __restrict__ lvec,
    float* __restrict__ outInit)
{
  __shared__ float tile[32][33];
  int b = blockIdx.x, tid = threadIdx.x;
  if (b < 4096) {                        // emb cast (float4/thread)
    int idx = b * 256 + tid;
    float4 v = ((const float4*)emb)[idx];
    ushort4 o; o.x = f2bf(v.x); o.y = f2bf(v.y); o.z = f2bf(v.z); o.w = f2bf(v.w);
    ((ushort4*)embB)[idx] = o;
    return;
  }
  int tx = tid & 31, ty = tid >> 5;
  if (b < 7168) {                        // Wq/Wk/Wv [1024,1024] -> WqkvT
    int local = b - 4096;
    const float* in = (local < 1024) ? Wq : (local < 2048) ? Wk : Wv;
    uint16_t* o = WqkvT + (size_t)(local >> 10) * 1048576;
    int rem = local & 1023;
    int r0 = (rem >> 5) * 32, c0 = (rem & 31) * 32;
#pragma unroll
    for (int r = 0; r < 32; r += 8)
      tile[ty + r][tx] = in[(size_t)(r0 + ty + r) * 1024 + c0 + tx];
    __syncthreads();
#pragma unroll
    for (int r = 0; r < 32; r += 8)
      o[(size_t)(c0 + ty + r) * 1024 + r0 + tx] = f2bf(tile[tx][ty + r]);
    return;
  }
  if (b < 11264) {                       // W1 [1024,4096] -> W1T [4096,1024]
    int local = b - 7168;
    int c0 = (local & 127) * 32, r0 = (local >> 7) * 32;
#pragma unroll
    for (int r = 0; r < 32; r += 8)
      tile[ty + r][tx] = W1[(size_t)(r0 + ty + r) * 4096 + c0 + tx];
    __syncthreads();
#pragma unroll
    for (int r = 0; r < 32; r += 8)
      W1T[(size_t)(c0 + ty + r) * 1024 + r0 + tx] = f2bf(tile[tx][ty + r]);
    return;
  }
  if (b < 15360) {                       // W2 [4096,1024] -> W2T [1024,4096]
    int local = b - 11264;
    int c0 = (local & 31) * 32, r0 = (local >> 5) * 32;
#pragma unroll
    for (int r = 0; r < 32; r += 8)
      tile[ty + r][tx] = W2[(size_t)(r0 + ty + r) * 1024 + c0 + tx];
    __syncthreads();
#pragma unroll
    for (int r = 0; r < 32; r += 8)
      W2T[(size_t)(c0 + ty + r) * 4096 + r0 + tx] = f2bf(tile[tx][ty + r]);
    return;
  }
  if (b < 15372) {                       // pack bq|bk|bv
    int i = (b - 15360) * 256 + tid;
    bqkv[i] = (i < 1024) ? bq[i] : (i < 2048) ? bk[i - 1024] : bv[i - 2048];
    return;
  }
  if (b == 15372) {                      // lvec = 0
#pragma unroll
    for (int i = tid; i < 4096; i += 256) lvec[i] = 0.0f;
    return;
  }
  {                                      // d_out row init = b2
    int row = b - 15373;
    float4 bv4 = ((const float4*)b2)[tid];
    ((float4*)(outInit + (size_t)row * 1024))[tid] = bv4;
  }
}

// ---------------- launcher --------------------------------------------------
extern "C" void kernel_launch(void* const* d_in, const int* in_sizes, int n_in,
                              void* d_out, int out_size, void* d_ws, size_t ws_size,
                              hipStream_t stream) {
  const float* emb   = (const float*)d_in[0];
  const float* Wq    = (const float*)d_in[1];
  const float* bq    = (const float*)d_in[2];
  const float* Wk    = (const float*)d_in[3];
  const float* bk    = (const float*)d_in[4];
  const float* Wv    = (const float*)d_in[5];
  const float* bv    = (const float*)d_in[6];
  const float* gamma = (const float*)d_in[7];
  const float* beta  = (const float*)d_in[8];
  const float* W1    = (const float*)d_in[9];
  const float* b1    = (const float*)d_in[10];
  const float* W2    = (const float*)d_in[11];
  const float* b2    = (const float*)d_in[12];

  char* w = (char*)d_ws;
  const size_t MB = 1ull << 20;
  uint16_t* embB  = (uint16_t*)(w + 0 * MB);    // [4096,1024] bf16
  uint16_t* WqkvT = (uint16_t*)(w + 8 * MB);    // [3072,1024] packed q|k|v
  uint16_t* W1T   = (uint16_t*)(w + 14 * MB);   // [4096,1024]
  uint16_t* W2T   = (uint16_t*)(w + 22 * MB);   // [1024,4096]
  float*    bqkv  = (float*)(w + 30 * MB);      // [3072]
  float*    lvec  = (float*)(w + 30 * MB + 65536); // [4096] softmax denominators
  uint16_t* QKVb  = (uint16_t*)(w + 31 * MB);   // [4096,3072] (V region unused)
  uint16_t* Vt    = (uint16_t*)(w + 55 * MB);   // [1024,4096]
  uint16_t* xB    = (uint16_t*)(w + 0 * MB);    // reuses embB (dead after QKV)
  uint16_t* hB    = (uint16_t*)(w + 63 * MB);   // [4096,4096] bf16
  uint16_t* Sb    = (uint16_t*)(w + 95 * MB);   // [4096,4096] bf16 exp(S)
  float*    Opart = (float*)(w + 63 * MB);      // [2][4096,1024] fp32 (pre-FFN1)
  // total ws requirement: 159 MB

  prep<<<19469, 256, 0, stream>>>(emb, Wq, Wk, Wv, W1, W2, bq, bk, bv, b2,
                                  embB, WqkvT, W1T, W2T, bqkv, lvec,
                                  (float*)d_out);

  // fused QKV: 768 blocks; Q,K -> QKVb (bias fused); V -> Vt transposed
  gemm_bt<<<dim3(24, 32), 256, 0, stream>>>(embB, WqkvT, bqkv, QKVb, Vt,
      1024, 1024, 1024, 3072, 1.0f, 1, 0);
  const uint16_t* Qb = QKVb;
  const uint16_t* Kb = QKVb + 1024;

  // exp(S) = exp(QK^T/sqrt(D)), 64x128 causal tiles + fused row-sum atomics
  gemm_s<<<1056, 256, 0, stream>>>(Qb, Kb, Sb, lvec, 3072, 3072, 4096, 0.03125f);

  // O' = exp(S) @ V (unnormalized), causal split-K=2 -> partials
  gemm_bt_n64<<<dim3(16, 64), 256, 0, stream>>>(Sb, Vt, Opart,
      4096, 4096, 4096, 1024, 2);

  // reduce O partials, /l, + residual, LayerNorm -> xB
  add_layernorm<<<4096, 256, 0, stream>>>(Opart, lvec, emb, gamma, beta, xB);

  gemm_bt<<<dim3(32, 32), 256, 0, stream>>>(xB, W1T, b1, hB, nullptr,
      1024, 1024, 1024, 4096, 1.0f, 1, 1);

  // FFN2 split-K=2, atomicAdd into d_out (pre-initialized with b2 by prep)
  gemm_bt_n64<<<dim3(16, 64), 256, 0, stream>>>(hB, W2T, d_out,
      4096, 4096, 4096, 1024, 4);
}

// Round 7
// 360.536 us; speedup vs baseline: 1.4626x; 1.0096x over previous
//
#include <hip/hip_runtime.h>
#include <stdint.h>

// Round 7: (a) XCD-locality swizzle (1-D grids, id%8 == f(A-chunk)) for FFN2
// and O so A-sharing blocks co-reside on one XCD's L2 (FETCH was 135MB vs
// 40MB unique = 82% HBM re-fetch). (b) O-gemm re-tiled 128x128 with
// triangular K-chunks (640 blocks, uniform iters, chunked partials; LN reads
// (row>>10)+1 chunks). (c) QKV V written transposed via in-LDS rotated tile
// transpose (coalesced 16B stores, replaces round-6 2B scatter).
// BK=64, XOR LDS swizzle, shift-free softmax retained. ws: 159 MB.

using short8 = __attribute__((ext_vector_type(8))) short;
using f32x4  = __attribute__((ext_vector_type(4))) float;

__device__ __forceinline__ uint16_t f2bf(float f) {
  uint32_t u = __builtin_bit_cast(uint32_t, f);
  u += 0x7FFFu + ((u >> 16) & 1u);        // RNE, inputs are finite
  return (uint16_t)(u >> 16);
}

__device__ __forceinline__ void gload_lds16(const uint16_t* g, uint16_t* l) {
  __builtin_amdgcn_global_load_lds(
      (__attribute__((address_space(1))) void*)(void*)g,
      (__attribute__((address_space(3))) void*)l, 16, 0, 0);
}

// LDS swizzle (BK=64): 16B slot s holds global chunk-col (s&7)^((s>>3)&7) of
// row s>>3. Read (row r, chunk cc) -> slot r*8 + (cc ^ (r&7)).

// ---------------- GEMM 128x128: C = scale*A@Bt^T + bias ---------------------
// 2-D grid. VtOut!=nullptr: bn>=16 blocks (V region) transpose their tile in
// LDS and store coalesced to VtOut[col-2048][row].
__global__ __launch_bounds__(256) void gemm_bt(
    const uint16_t* __restrict__ A, const uint16_t* __restrict__ Bt,
    const float* __restrict__ bias, void* __restrict__ Cout,
    uint16_t* __restrict__ VtOut,
    int K, int lda, int ldb, int ldc,
    float scale, int out_bf16, int relu)
{
  constexpr int BK = 64;
  __shared__ uint16_t smem[2 * 128 * BK];          // As | Bs ; aliased as T
  uint16_t* As = smem;
  uint16_t* Bs = smem + 128 * BK;
  int bm = blockIdx.y, bn = blockIdx.x;

  int tid  = threadIdx.x;
  int lane = tid & 63;
  int wave = tid >> 6;
  int wm = (wave >> 1) * 64, wn = (wave & 1) * 64;
  int lr = lane & 15, quad = lane >> 4;

  const uint16_t *Ag[4], *Bg[4];
  uint16_t *Al[4], *Bl[4];
#pragma unroll
  for (int s = 0; s < 4; ++s) {
    int c = tid + 256 * s;
    int r = c >> 3, q = (c & 7) ^ (r & 7);
    Ag[s] = A  + (size_t)(bm * 128 + r) * lda + q * 8;
    Bg[s] = Bt + (size_t)(bn * 128 + r) * ldb + q * 8;
    Al[s] = As + c * 8;
    Bl[s] = Bs + c * 8;
  }

  f32x4 acc[4][4] = {};

  for (int k0 = 0; k0 < K; k0 += BK) {
    __syncthreads();
#pragma unroll
    for (int s = 0; s < 4; ++s) gload_lds16(Ag[s] + k0, Al[s]);
#pragma unroll
    for (int s = 0; s < 4; ++s) gload_lds16(Bg[s] + k0, Bl[s]);
    __syncthreads();
#pragma unroll
    for (int h = 0; h < 2; ++h) {
      short8 af[4], bfr[4];
      int cc = quad + 4 * h;
#pragma unroll
      for (int i = 0; i < 4; ++i) {
        int r = wm + i * 16 + lr;
        af[i] = *(const short8*)(&As[(r * 8 + (cc ^ (r & 7))) * 8]);
      }
#pragma unroll
      for (int j = 0; j < 4; ++j) {
        int r = wn + j * 16 + lr;
        bfr[j] = *(const short8*)(&Bs[(r * 8 + (cc ^ (r & 7))) * 8]);
      }
#pragma unroll
      for (int i = 0; i < 4; ++i)
#pragma unroll
        for (int j = 0; j < 4; ++j)
          acc[i][j] = __builtin_amdgcn_mfma_f32_16x16x32_bf16(af[i], bfr[j], acc[i][j], 0, 0, 0);
    }
  }

  int row0 = bm * 128 + wm + quad * 4;
  int col0 = bn * 128 + wn + lr;

  if (VtOut && bn >= 16) {
    // transpose tile in LDS: T[cl][rl] at elem cl*128 + ((rl + 8*cl) & 127)
    __syncthreads();                               // K-loop LDS reads done
#pragma unroll
    for (int j = 0; j < 4; ++j) {
      int cl = wn + j * 16 + lr;
      float bv = bias ? bias[bn * 128 + cl] : 0.0f;
#pragma unroll
      for (int i = 0; i < 4; ++i)
#pragma unroll
        for (int r = 0; r < 4; ++r) {
          int rl = wm + quad * 4 + i * 16 + r;
          smem[cl * 128 + ((rl + 8 * cl) & 127)] = f2bf(acc[i][j][r] * scale + bv);
        }
    }
    __syncthreads();
    int cl = tid >> 1, rb = (tid & 1) * 64;        // thread: 64 elems of row cl
    uint16_t* dst = VtOut + (size_t)((bn - 16) * 128 + cl) * 4096 + bm * 128;
#pragma unroll
    for (int k = 0; k < 8; ++k) {
      int rl = rb + k * 8;
      short8 v = *(const short8*)(&smem[cl * 128 + ((rl + 8 * cl) & 127)]);
      *(short8*)(dst + rl) = v;
    }
    return;
  }

#pragma unroll
  for (int j = 0; j < 4; ++j) {
    int col = col0 + j * 16;
    float bv = bias ? bias[col] : 0.0f;
#pragma unroll
    for (int i = 0; i < 4; ++i) {
#pragma unroll
      for (int r = 0; r < 4; ++r) {
        int row = row0 + i * 16 + r;
        float v = acc[i][j][r] * scale + bv;
        if (relu) v = fmaxf(v, 0.0f);
        size_t idx = (size_t)row * ldc + col;
        if (out_bf16) ((uint16_t*)Cout)[idx] = f2bf(v);
        else          ((float*)Cout)[idx]    = v;
      }
    }
  }
}

// ---------------- causal S-gemm, 64x128 tiles: Sb = exp(scale*Q@K^T) --------
// 1-D grid of 1056 lower-triangle tiles; fused row-sum atomics into lvec.
__global__ __launch_bounds__(256) void gemm_s(
    const uint16_t* __restrict__ Qm, const uint16_t* __restrict__ Km,
    uint16_t* __restrict__ Sb, float* __restrict__ lvec,
    int lda, int ldb, int ldc, float scale)
{
  constexpr int BK = 64;
  __shared__ uint16_t As[64 * BK];
  __shared__ uint16_t Bs[128 * BK];
  int t = blockIdx.x;
  int u = (int)sqrtf((float)t);
  while ((u + 1) * (u + 1) <= t) ++u;
  while (u * u > t) --u;
  int i64, bn;
  if (t < u * (u + 1)) { i64 = 2 * u - 1; bn = t - u * u; }
  else                 { i64 = 2 * u;     bn = t - u * (u + 1); }

  int tid  = threadIdx.x;
  int lane = tid & 63;
  int wave = tid >> 6;
  int wm = (wave >> 1) * 32, wn = (wave & 1) * 64;   // wave: 32 rows x 64 cols
  int lr = lane & 15, quad = lane >> 4;

  const uint16_t *Ag[2], *Bg[4];
  uint16_t *Al[2], *Bl[4];
#pragma unroll
  for (int s = 0; s < 2; ++s) {
    int c = tid + 256 * s;
    int r = c >> 3, q = (c & 7) ^ (r & 7);
    Ag[s] = Qm + (size_t)(i64 * 64 + r) * lda + q * 8;
    Al[s] = As + c * 8;
  }
#pragma unroll
  for (int s = 0; s < 4; ++s) {
    int c = tid + 256 * s;
    int r = c >> 3, q = (c & 7) ^ (r & 7);
    Bg[s] = Km + (size_t)(bn * 128 + r) * ldb + q * 8;
    Bl[s] = Bs + c * 8;
  }

  f32x4 acc[2][4] = {};

  for (int k0 = 0; k0 < 1024; k0 += BK) {
    __syncthreads();
#pragma unroll
    for (int s = 0; s < 2; ++s) gload_lds16(Ag[s] + k0, Al[s]);
#pragma unroll
    for (int s = 0; s < 4; ++s) gload_lds16(Bg[s] + k0, Bl[s]);
    __syncthreads();
#pragma unroll
    for (int h = 0; h < 2; ++h) {
      short8 af[2], bfr[4];
      int cc = quad + 4 * h;
#pragma unroll
      for (int i = 0; i < 2; ++i) {
        int r = wm + i * 16 + lr;
        af[i] = *(const short8*)(&As[(r * 8 + (cc ^ (r & 7))) * 8]);
      }
#pragma unroll
      for (int j = 0; j < 4; ++j) {
        int r = wn + j * 16 + lr;
        bfr[j] = *(const short8*)(&Bs[(r * 8 + (cc ^ (r & 7))) * 8]);
      }
#pragma unroll
      for (int i = 0; i < 2; ++i)
#pragma unroll
        for (int j = 0; j < 4; ++j)
          acc[i][j] = __builtin_amdgcn_mfma_f32_16x16x32_bf16(af[i], bfr[j], acc[i][j], 0, 0, 0);
    }
  }

  int row0 = i64 * 64 + wm + quad * 4;
  int col0 = bn * 128 + wn + lr;
#pragma unroll
  for (int i = 0; i < 2; ++i) {
#pragma unroll
    for (int r = 0; r < 4; ++r) {
      int row = row0 + i * 16 + r;
      float s = 0.0f;
#pragma unroll
      for (int j = 0; j < 4; ++j) {
        int col = col0 + j * 16;
        float v = (col <= row) ? __expf(acc[i][j][r] * scale) : 0.0f;
        Sb[(size_t)row * ldc + col] = f2bf(v);
        s += v;
      }
#pragma unroll
      for (int o = 8; o > 0; o >>= 1) s += __shfl_xor(s, o, 64);
      if (lr == 0) unsafeAtomicAdd(&lvec[row], s);
    }
  }
}

// ---------------- O-gemm: 128x128, triangular K-chunks, XCD-swizzled --------
// 1-D grid 640: id = bn*80 + p (80%8==0 -> id%8==p%8, A-sharing blocks
// co-XCD). p -> (c,bm): c=0 bm=p(0..31); c=1 bm=p-24(8..31); c=2 bm=p-40
// (16..31); c=3 bm=p-48(24..31). K range [c*1024, min((bm+1)*128,(c+1)*1024)).
// fp32 partials at Opart + c*4096*1024.
__global__ __launch_bounds__(256) void gemm_o(
    const uint16_t* __restrict__ Sb, const uint16_t* __restrict__ Vt,
    float* __restrict__ Opart)
{
  constexpr int BK = 64;
  __shared__ uint16_t As[128 * BK];
  __shared__ uint16_t Bs[128 * BK];
  int id = blockIdx.x;
  int bn = id / 80, p = id % 80;
  int c, bm;
  if      (p < 32) { c = 0; bm = p; }
  else if (p < 56) { c = 1; bm = p - 24; }
  else if (p < 72) { c = 2; bm = p - 40; }
  else             { c = 3; bm = p - 48; }
  int klo = c << 10;
  int khi = (bm + 1) << 7; if (khi > ((c + 1) << 10)) khi = (c + 1) << 10;

  int tid  = threadIdx.x;
  int lane = tid & 63;
  int wave = tid >> 6;
  int wm = (wave >> 1) * 64, wn = (wave & 1) * 64;
  int lr = lane & 15, quad = lane >> 4;

  const uint16_t *Ag[4], *Bg[4];
  uint16_t *Al[4], *Bl[4];
#pragma unroll
  for (int s = 0; s < 4; ++s) {
    int cch = tid + 256 * s;
    int r = cch >> 3, q = (cch & 7) ^ (r & 7);
    Ag[s] = Sb + (size_t)(bm * 128 + r) * 4096 + q * 8;
    Bg[s] = Vt + (size_t)(bn * 128 + r) * 4096 + q * 8;
    Al[s] = As + cch * 8;
    Bl[s] = Bs + cch * 8;
  }

  f32x4 acc[4][4] = {};

  for (int k0 = klo; k0 < khi; k0 += BK) {
    __syncthreads();
#pragma unroll
    for (int s = 0; s < 4; ++s) gload_lds16(Ag[s] + k0, Al[s]);
#pragma unroll
    for (int s = 0; s < 4; ++s) gload_lds16(Bg[s] + k0, Bl[s]);
    __syncthreads();
#pragma unroll
    for (int h = 0; h < 2; ++h) {
      short8 af[4], bfr[4];
      int cc = quad + 4 * h;
#pragma unroll
      for (int i = 0; i < 4; ++i) {
        int r = wm + i * 16 + lr;
        af[i] = *(const short8*)(&As[(r * 8 + (cc ^ (r & 7))) * 8]);
      }
#pragma unroll
      for (int j = 0; j < 4; ++j) {
        int r = wn + j * 16 + lr;
        bfr[j] = *(const short8*)(&Bs[(r * 8 + (cc ^ (r & 7))) * 8]);
      }
#pragma unroll
      for (int i = 0; i < 4; ++i)
#pragma unroll
        for (int j = 0; j < 4; ++j)
          acc[i][j] = __builtin_amdgcn_mfma_f32_16x16x32_bf16(af[i], bfr[j], acc[i][j], 0, 0, 0);
    }
  }

  float* P = Opart + (size_t)c * 4194304;
  int row0 = bm * 128 + wm + quad * 4;
  int col0 = bn * 128 + wn + lr;
#pragma unroll
  for (int j = 0; j < 4; ++j)
#pragma unroll
    for (int i = 0; i < 4; ++i)
#pragma unroll
      for (int r = 0; r < 4; ++r)
        P[(size_t)(row0 + i * 16 + r) * 1024 + col0 + j * 16] = acc[i][j][r];
}

// ---------------- FFN2: 128x64, split-K=2, atomic epilogue, XCD-swizzled ----
// 1-D grid 1024: id = bn*64 + p (64%8==0 -> id%8==p%8). p -> bm=p>>1,
// half=p&1. unsafeAtomicAdd into fp32 Cout (pre-initialized with b2 by prep).
__global__ __launch_bounds__(256) void gemm_ffn2(
    const uint16_t* __restrict__ A, const uint16_t* __restrict__ Bt,
    float* __restrict__ Cout)
{
  constexpr int BK = 64;
  __shared__ uint16_t As[128 * BK];
  __shared__ uint16_t Bs[64 * BK];
  int id = blockIdx.x;
  int bn = id >> 6, p = id & 63;
  int bm = p >> 1, half = p & 1;
  int klo = half ? 2048 : 0, khi = half ? 4096 : 2048;

  int tid  = threadIdx.x;
  int lane = tid & 63;
  int wave = tid >> 6;
  int wm = (wave & 1) * 64, wn = (wave >> 1) * 32;   // wave: 64 rows x 32 cols
  int lr = lane & 15, quad = lane >> 4;

  const uint16_t *Ag[4], *Bg[2];
  uint16_t *Al[4], *Bl[2];
#pragma unroll
  for (int s = 0; s < 4; ++s) {
    int c = tid + 256 * s;
    int r = c >> 3, q = (c & 7) ^ (r & 7);
    Ag[s] = A + (size_t)(bm * 128 + r) * 4096 + q * 8;
    Al[s] = As + c * 8;
  }
#pragma unroll
  for (int s = 0; s < 2; ++s) {
    int c = tid + 256 * s;
    int r = c >> 3, q = (c & 7) ^ (r & 7);
    Bg[s] = Bt + (size_t)(bn * 64 + r) * 4096 + q * 8;
    Bl[s] = Bs + c * 8;
  }

  f32x4 acc[4][2] = {};

  for (int k0 = klo; k0 < khi; k0 += BK) {
    __syncthreads();
#pragma unroll
    for (int s = 0; s < 4; ++s) gload_lds16(Ag[s] + k0, Al[s]);
#pragma unroll
    for (int s = 0; s < 2; ++s) gload_lds16(Bg[s] + k0, Bl[s]);
    __syncthreads();
#pragma unroll
    for (int h = 0; h < 2; ++h) {
      short8 af[4], bfr[2];
      int cc = quad + 4 * h;
#pragma unroll
      for (int i = 0; i < 4; ++i) {
        int r = wm + i * 16 + lr;
        af[i] = *(const short8*)(&As[(r * 8 + (cc ^ (r & 7))) * 8]);
      }
#pragma unroll
      for (int j = 0; j < 2; ++j) {
        int r = wn + j * 16 + lr;
        bfr[j] = *(const short8*)(&Bs[(r * 8 + (cc ^ (r & 7))) * 8]);
      }
#pragma unroll
      for (int i = 0; i < 4; ++i)
#pragma unroll
        for (int j = 0; j < 2; ++j)
          acc[i][j] = __builtin_amdgcn_mfma_f32_16x16x32_bf16(af[i], bfr[j], acc[i][j], 0, 0, 0);
    }
  }

  int row0 = bm * 128 + wm + quad * 4;
  int col0 = bn * 64 + wn + lr;
#pragma unroll
  for (int j = 0; j < 2; ++j)
#pragma unroll
    for (int i = 0; i < 4; ++i)
#pragma unroll
      for (int r = 0; r < 4; ++r) {
        size_t idx = (size_t)(row0 + i * 16 + r) * 1024 + col0 + j * 16;
        unsafeAtomicAdd(&Cout[idx], acc[i][j][r]);
      }
}

// ---------------- reductions ------------------------------------------------
__device__ __forceinline__ float block_sum(float v, float* red) {
#pragma unroll
  for (int o = 32; o > 0; o >>= 1) v += __shfl_xor(v, o, 64);
  if ((threadIdx.x & 63) == 0) red[threadIdx.x >> 6] = v;
  __syncthreads();
  v = red[0] + red[1] + red[2] + red[3];
  __syncthreads();
  return v;
}

// ------ O-chunk-partials reduce /l + residual + LayerNorm -> bf16 -----------
__global__ __launch_bounds__(256) void add_layernorm(
    const float* __restrict__ P, const float* __restrict__ l,
    const float* __restrict__ emb, const float* __restrict__ gamma,
    const float* __restrict__ beta, uint16_t* __restrict__ xB)
{
  __shared__ float red[4];
  int i = blockIdx.x, tid = threadIdx.x;
  float inv_l = 1.0f / l[i];
  int nc = (i >> 10) + 1;                  // chunks contributing to this row
  float s0 = 0.0f, s1 = 0.0f, s2 = 0.0f, s3 = 0.0f;
  for (int c = 0; c < nc; ++c) {
    float4 a = ((const float4*)(P + (size_t)c * 4194304 + (size_t)i * 1024))[tid];
    s0 += a.x; s1 += a.y; s2 += a.z; s3 += a.w;
  }
  float4 b = ((const float4*)(emb + (size_t)i * 1024))[tid];
  float x0 = s0 * inv_l + b.x, x1 = s1 * inv_l + b.y;
  float x2 = s2 * inv_l + b.z, x3 = s3 * inv_l + b.w;
  float mu = block_sum(x0 + x1 + x2 + x3, red) * (1.0f / 1024.0f);
  float d0 = x0 - mu, d1 = x1 - mu, d2 = x2 - mu, d3 = x3 - mu;
  float var = block_sum(d0 * d0 + d1 * d1 + d2 * d2 + d3 * d3, red) * (1.0f / 1024.0f);
  float rs = rsqrtf(var + 1e-5f);
  float4 g  = ((const float4*)gamma)[tid];
  float4 be = ((const float4*)beta)[tid];
  ushort4 o;
  o.x = f2bf(d0 * rs * g.x + be.x);
  o.y = f2bf(d1 * rs * g.y + be.y);
  o.z = f2bf(d2 * rs * g.z + be.z);
  o.w = f2bf(d3 * rs * g.w + be.w);
  ((ushort4*)(xB + (size_t)i * 1024))[tid] = o;
}

// ---------------- prep: all casts/transposes/bias/init in one launch --------
__global__ __launch_bounds__(256) void prep(
    const float* __restrict__ emb, const float* __restrict__ Wq,
    const float* __restrict__ Wk, const float* __restrict__ Wv,
    const float* __restrict__ W1, const float* __restrict__ W2,
    const float* __restrict__ bq, const float* __restrict__ bk,
    const float* __restrict__ bv, const float* __restrict__ b2,
    uint16_t* __restrict__ embB, uint16_t* __restrict__ WqkvT,
    uint16_t* __restrict__ W1T, uint16_t* __restrict__ W2T,
    float* __restrict__ bqkv, float* __restrict__ lvec,
    float* __restrict__ outInit)
{
  __shared__ float tile[32][33];
  int b = blockIdx.x, tid = threadIdx.x;
  if (b < 4096) {                        // emb cast
    int idx = b * 256 + tid;
    float4 v = ((const float4*)emb)[idx];
    ushort4 o; o.x = f2bf(v.x); o.y = f2bf(v.y); o.z = f2bf(v.z); o.w = f2bf(v.w);
    ((ushort4*)embB)[idx] = o;
    return;
  }
  int tx = tid & 31, ty = tid >> 5;
  if (b < 7168) {                        // Wq/Wk/Wv -> WqkvT
    int local = b - 4096;
    const float* in = (local < 1024) ? Wq : (local < 2048) ? Wk : Wv;
    uint16_t* o = WqkvT + (size_t)(local >> 10) * 1048576;
    int rem = local & 1023;
    int r0 = (rem >> 5) * 32, c0 = (rem & 31) * 32;
#pragma unroll
    for (int r = 0; r < 32; r += 8)
      tile[ty + r][tx] = in[(size_t)(r0 + ty + r) * 1024 + c0 + tx];
    __syncthreads();
#pragma unroll
    for (int r = 0; r < 32; r += 8)
      o[(size_t)(c0 + ty + r) * 1024 + r0 + tx] = f2bf(tile[tx][ty + r]);
    return;
  }
  if (b < 11264) {                       // W1 -> W1T
    int local = b - 7168;
    int c0 = (local & 127) * 32, r0 = (local >> 7) * 32;
#pragma unroll
    for (int r = 0; r < 32; r += 8)
      tile[ty + r][tx] = W1[(size_t)(r0 + ty + r) * 4096 + c0 + tx];
    __syncthreads();
#pragma unroll
    for (int r = 0; r < 32; r += 8)
      W1T[(size_t)(c0 + ty + r) * 1024 + r0 + tx] = f2bf(tile[tx][ty + r]);
    return;
  }
  if (b < 15360) {                       // W2 -> W2T
    int local = b - 11264;
    int c0 = (local & 31) * 32, r0 = (local >> 5) * 32;
#pragma unroll
    for (int r = 0; r < 32; r += 8)
      tile[ty + r][tx] = W2[(size_t)(r0 + ty + r) * 1024 + c0 + tx];
    __syncthreads();
#pragma unroll
    for (int r = 0; r < 32; r += 8)
      W2T[(size_t)(c0 + ty + r) * 4096 + r0 + tx] = f2bf(tile[tx][ty + r]);
    return;
  }
  if (b < 15372) {                       // pack bq|bk|bv
    int i = (b - 15360) * 256 + tid;
    bqkv[i] = (i < 1024) ? bq[i] : (i < 2048) ? bk[i - 1024] : bv[i - 2048];
    return;
  }
  if (b == 15372) {                      // lvec = 0
#pragma unroll
    for (int i = tid; i < 4096; i += 256) lvec[i] = 0.0f;
    return;
  }
  {                                      // d_out row init = b2
    int row = b - 15373;
    float4 bv4 = ((const float4*)b2)[tid];
    ((float4*)(outInit + (size_t)row * 1024))[tid] = bv4;
  }
}

// ---------------- launcher --------------------------------------------------
extern "C" void kernel_launch(void* const* d_in, const int* in_sizes, int n_in,
                              void* d_out, int out_size, void* d_ws, size_t ws_size,
                              hipStream_t stream) {
  const float* emb   = (const float*)d_in[0];
  const float* Wq    = (const float*)d_in[1];
  const float* bq    = (const float*)d_in[2];
  const float* Wk    = (const float*)d_in[3];
  const float* bk    = (const float*)d_in[4];
  const float* Wv    = (const float*)d_in[5];
  const float* bv    = (const float*)d_in[6];
  const float* gamma = (const float*)d_in[7];
  const float* beta  = (const float*)d_in[8];
  const float* W1    = (const float*)d_in[9];
  const float* b1    = (const float*)d_in[10];
  const float* W2    = (const float*)d_in[11];
  const float* b2    = (const float*)d_in[12];

  char* w = (char*)d_ws;
  const size_t MB = 1ull << 20;
  uint16_t* embB  = (uint16_t*)(w + 0 * MB);    // [4096,1024] bf16
  uint16_t* WqkvT = (uint16_t*)(w + 8 * MB);    // [3072,1024]
  uint16_t* W1T   = (uint16_t*)(w + 14 * MB);   // [4096,1024]
  uint16_t* W2T   = (uint16_t*)(w + 22 * MB);   // [1024,4096]
  float*    bqkv  = (float*)(w + 30 * MB);      // [3072]
  float*    lvec  = (float*)(w + 30 * MB + 65536); // [4096]
  uint16_t* QKVb  = (uint16_t*)(w + 31 * MB);   // [4096,3072] (V cols unused)
  uint16_t* Vt    = (uint16_t*)(w + 55 * MB);   // [1024,4096]
  uint16_t* Sb    = (uint16_t*)(w + 63 * MB);   // [4096,4096] bf16 exp(S)
  uint16_t* hB    = (uint16_t*)(w + 63 * MB);   // reuses Sb (dead after O)
  float*    Opart = (float*)(w + 95 * MB);      // [4][4096,1024] fp32 chunks
  uint16_t* xB    = (uint16_t*)(w + 0 * MB);    // reuses embB
  // total ws requirement: 159 MB

  prep<<<19469, 256, 0, stream>>>(emb, Wq, Wk, Wv, W1, W2, bq, bk, bv, b2,
                                  embB, WqkvT, W1T, W2T, bqkv, lvec,
                                  (float*)d_out);

  // fused QKV: Q,K -> QKVb (bias fused); V -> Vt via in-LDS transpose
  gemm_bt<<<dim3(24, 32), 256, 0, stream>>>(embB, WqkvT, bqkv, QKVb, Vt,
      1024, 1024, 1024, 3072, 1.0f, 1, 0);
  const uint16_t* Qb = QKVb;
  const uint16_t* Kb = QKVb + 1024;

  // exp(S) = exp(QK^T/sqrt(D)), 64x128 causal tiles + fused row-sum atomics
  gemm_s<<<1056, 256, 0, stream>>>(Qb, Kb, Sb, lvec, 3072, 3072, 4096, 0.03125f);

  // O' = exp(S) @ V: 128x128 triangular K-chunks, XCD-swizzled, 640 blocks
  gemm_o<<<640, 256, 0, stream>>>(Sb, Vt, Opart);

  // reduce O chunk-partials, /l, + residual, LayerNorm -> xB
  add_layernorm<<<4096, 256, 0, stream>>>(Opart, lvec, emb, gamma, beta, xB);

  gemm_bt<<<dim3(32, 32), 256, 0, stream>>>(xB, W1T, b1, hB, nullptr,
      1024, 1024, 1024, 4096, 1.0f, 1, 1);

  // FFN2: XCD-swizzled split-K=2, atomicAdd into b2-initialized d_out
  gemm_ffn2<<<1024, 256, 0, stream>>>(hB, W2T, (float*)d_out);
}

// Round 8
// 341.215 us; speedup vs baseline: 1.5454x; 1.0566x over previous
//
#include <hip/hip_runtime.h>
#include <stdint.h>

// Round 8: de-regress the shared gemm. (a) gemm_qkv is its own kernel; V
// blocks (bn>=16) use OPERAND-SWAPPED MFMA (D = W·X^T) so the tile comes out
// already transposed — epilogue stores to Vt are 32B-contiguous, no LDS
// transpose, no VGPR bloat (round-7: VGPR 100->112 cost ~15us on BOTH QKV
// and FFN1). (b) FFN1 back to the slim kernel. (c) 1-D XCD-swizzled grids
// (id%8 == bm%8) for QKV/FFN1 so A-sharing blocks co-reside per XCD.
// gemm_s / gemm_o / gemm_ffn2 / prep / add_layernorm unchanged from R7.
// BK=64, XOR LDS swizzle, shift-free softmax. ws: 159 MB.

using short8 = __attribute__((ext_vector_type(8))) short;
using f32x4  = __attribute__((ext_vector_type(4))) float;

__device__ __forceinline__ uint16_t f2bf(float f) {
  uint32_t u = __builtin_bit_cast(uint32_t, f);
  u += 0x7FFFu + ((u >> 16) & 1u);        // RNE, inputs are finite
  return (uint16_t)(u >> 16);
}

__device__ __forceinline__ void gload_lds16(const uint16_t* g, uint16_t* l) {
  __builtin_amdgcn_global_load_lds(
      (__attribute__((address_space(1))) void*)(void*)g,
      (__attribute__((address_space(3))) void*)l, 16, 0, 0);
}

// LDS swizzle (BK=64): 16B slot s holds global chunk-col (s&7)^((s>>3)&7) of
// row s>>3. Read (row r, chunk cc) -> slot r*8 + (cc ^ (r&7)).

// ---------------- QKV gemm: 128x128, 1-D grid 768 (id%8==bm%8) --------------
// bn<16: C[m][n] -> QKVb (bias fused, bf16). bn>=16 (V): operand-swapped
// MFMA gives D[n][m]; store straight to Vt[n][m] (32B-contiguous in m).
__global__ __launch_bounds__(256) void gemm_qkv(
    const uint16_t* __restrict__ A, const uint16_t* __restrict__ Bt,
    const float* __restrict__ bias, uint16_t* __restrict__ Cout,
    uint16_t* __restrict__ Vt)
{
  constexpr int BK = 64;
  __shared__ uint16_t As[128 * BK];
  __shared__ uint16_t Bs[128 * BK];
  int id = blockIdx.x;
  int bm = id & 31, bn = id >> 5;
  bool vblk = (bn >= 16);

  int tid  = threadIdx.x;
  int lane = tid & 63;
  int wave = tid >> 6;
  int wm = (wave >> 1) * 64, wn = (wave & 1) * 64;
  int lr = lane & 15, quad = lane >> 4;

  const uint16_t *Ag[4], *Bg[4];
  uint16_t *Al[4], *Bl[4];
#pragma unroll
  for (int s = 0; s < 4; ++s) {
    int c = tid + 256 * s;
    int r = c >> 3, q = (c & 7) ^ (r & 7);
    Ag[s] = A  + (size_t)(bm * 128 + r) * 1024 + q * 8;
    Bg[s] = Bt + (size_t)(bn * 128 + r) * 1024 + q * 8;
    Al[s] = As + c * 8;
    Bl[s] = Bs + c * 8;
  }
  // fragment sources: normal (af=emb rows, bfr=weight rows); vblk swapped
  const uint16_t* Fa = vblk ? Bs : As;
  const uint16_t* Fb = vblk ? As : Bs;

  f32x4 acc[4][4] = {};

  for (int k0 = 0; k0 < 1024; k0 += BK) {
    __syncthreads();
#pragma unroll
    for (int s = 0; s < 4; ++s) gload_lds16(Ag[s] + k0, Al[s]);
#pragma unroll
    for (int s = 0; s < 4; ++s) gload_lds16(Bg[s] + k0, Bl[s]);
    __syncthreads();
#pragma unroll
    for (int h = 0; h < 2; ++h) {
      short8 af[4], bfr[4];
      int cc = quad + 4 * h;
#pragma unroll
      for (int i = 0; i < 4; ++i) {
        int r = wm + i * 16 + lr;
        af[i] = *(const short8*)(&Fa[(r * 8 + (cc ^ (r & 7))) * 8]);
      }
#pragma unroll
      for (int j = 0; j < 4; ++j) {
        int r = wn + j * 16 + lr;
        bfr[j] = *(const short8*)(&Fb[(r * 8 + (cc ^ (r & 7))) * 8]);
      }
#pragma unroll
      for (int i = 0; i < 4; ++i)
#pragma unroll
        for (int j = 0; j < 4; ++j)
          acc[i][j] = __builtin_amdgcn_mfma_f32_16x16x32_bf16(af[i], bfr[j], acc[i][j], 0, 0, 0);
    }
  }

  if (vblk) {
    // D rows = weight idx (Bs): bn*128 + wm + i*16 + quad*4 + r
    // D cols = emb   idx (As): bm*128 + wn + j*16 + lr
#pragma unroll
    for (int i = 0; i < 4; ++i) {
#pragma unroll
      for (int r = 0; r < 4; ++r) {
        int n = bn * 128 + wm + i * 16 + quad * 4 + r;
        float bv = bias[n];
        uint16_t* dst = Vt + (size_t)(n - 2048) * 4096 + bm * 128;
#pragma unroll
        for (int j = 0; j < 4; ++j)
          dst[wn + j * 16 + lr] = f2bf(acc[i][j][r] + bv);
      }
    }
  } else {
    int row0 = bm * 128 + wm + quad * 4;
    int col0 = bn * 128 + wn + lr;
#pragma unroll
    for (int j = 0; j < 4; ++j) {
      int col = col0 + j * 16;
      float bv = bias[col];
#pragma unroll
      for (int i = 0; i < 4; ++i)
#pragma unroll
        for (int r = 0; r < 4; ++r)
          Cout[(size_t)(row0 + i * 16 + r) * 3072 + col] = f2bf(acc[i][j][r] + bv);
    }
  }
}

// ---------------- FFN1 gemm: 128x128, 1-D grid 1024 (id%8==bm%8) ------------
// C = relu(A@Bt^T + bias) -> bf16.
__global__ __launch_bounds__(256) void gemm_ffn1(
    const uint16_t* __restrict__ A, const uint16_t* __restrict__ Bt,
    const float* __restrict__ bias, uint16_t* __restrict__ Cout)
{
  constexpr int BK = 64;
  __shared__ uint16_t As[128 * BK];
  __shared__ uint16_t Bs[128 * BK];
  int id = blockIdx.x;
  int bm = id & 31, bn = id >> 5;

  int tid  = threadIdx.x;
  int lane = tid & 63;
  int wave = tid >> 6;
  int wm = (wave >> 1) * 64, wn = (wave & 1) * 64;
  int lr = lane & 15, quad = lane >> 4;

  const uint16_t *Ag[4], *Bg[4];
  uint16_t *Al[4], *Bl[4];
#pragma unroll
  for (int s = 0; s < 4; ++s) {
    int c = tid + 256 * s;
    int r = c >> 3, q = (c & 7) ^ (r & 7);
    Ag[s] = A  + (size_t)(bm * 128 + r) * 1024 + q * 8;
    Bg[s] = Bt + (size_t)(bn * 128 + r) * 1024 + q * 8;
    Al[s] = As + c * 8;
    Bl[s] = Bs + c * 8;
  }

  f32x4 acc[4][4] = {};

  for (int k0 = 0; k0 < 1024; k0 += BK) {
    __syncthreads();
#pragma unroll
    for (int s = 0; s < 4; ++s) gload_lds16(Ag[s] + k0, Al[s]);
#pragma unroll
    for (int s = 0; s < 4; ++s) gload_lds16(Bg[s] + k0, Bl[s]);
    __syncthreads();
#pragma unroll
    for (int h = 0; h < 2; ++h) {
      short8 af[4], bfr[4];
      int cc = quad + 4 * h;
#pragma unroll
      for (int i = 0; i < 4; ++i) {
        int r = wm + i * 16 + lr;
        af[i] = *(const short8*)(&As[(r * 8 + (cc ^ (r & 7))) * 8]);
      }
#pragma unroll
      for (int j = 0; j < 4; ++j) {
        int r = wn + j * 16 + lr;
        bfr[j] = *(const short8*)(&Bs[(r * 8 + (cc ^ (r & 7))) * 8]);
      }
#pragma unroll
      for (int i = 0; i < 4; ++i)
#pragma unroll
        for (int j = 0; j < 4; ++j)
          acc[i][j] = __builtin_amdgcn_mfma_f32_16x16x32_bf16(af[i], bfr[j], acc[i][j], 0, 0, 0);
    }
  }

  int row0 = bm * 128 + wm + quad * 4;
  int col0 = bn * 128 + wn + lr;
#pragma unroll
  for (int j = 0; j < 4; ++j) {
    int col = col0 + j * 16;
    float bv = bias[col];
#pragma unroll
    for (int i = 0; i < 4; ++i)
#pragma unroll
      for (int r = 0; r < 4; ++r)
        Cout[(size_t)(row0 + i * 16 + r) * 4096 + col] =
            f2bf(fmaxf(acc[i][j][r] + bv, 0.0f));
  }
}

// ---------------- causal S-gemm, 64x128 tiles: Sb = exp(scale*Q@K^T) --------
__global__ __launch_bounds__(256) void gemm_s(
    const uint16_t* __restrict__ Qm, const uint16_t* __restrict__ Km,
    uint16_t* __restrict__ Sb, float* __restrict__ lvec,
    int lda, int ldb, int ldc, float scale)
{
  constexpr int BK = 64;
  __shared__ uint16_t As[64 * BK];
  __shared__ uint16_t Bs[128 * BK];
  int t = blockIdx.x;
  int u = (int)sqrtf((float)t);
  while ((u + 1) * (u + 1) <= t) ++u;
  while (u * u > t) --u;
  int i64, bn;
  if (t < u * (u + 1)) { i64 = 2 * u - 1; bn = t - u * u; }
  else                 { i64 = 2 * u;     bn = t - u * (u + 1); }

  int tid  = threadIdx.x;
  int lane = tid & 63;
  int wave = tid >> 6;
  int wm = (wave >> 1) * 32, wn = (wave & 1) * 64;
  int lr = lane & 15, quad = lane >> 4;

  const uint16_t *Ag[2], *Bg[4];
  uint16_t *Al[2], *Bl[4];
#pragma unroll
  for (int s = 0; s < 2; ++s) {
    int c = tid + 256 * s;
    int r = c >> 3, q = (c & 7) ^ (r & 7);
    Ag[s] = Qm + (size_t)(i64 * 64 + r) * lda + q * 8;
    Al[s] = As + c * 8;
  }
#pragma unroll
  for (int s = 0; s < 4; ++s) {
    int c = tid + 256 * s;
    int r = c >> 3, q = (c & 7) ^ (r & 7);
    Bg[s] = Km + (size_t)(bn * 128 + r) * ldb + q * 8;
    Bl[s] = Bs + c * 8;
  }

  f32x4 acc[2][4] = {};

  for (int k0 = 0; k0 < 1024; k0 += BK) {
    __syncthreads();
#pragma unroll
    for (int s = 0; s < 2; ++s) gload_lds16(Ag[s] + k0, Al[s]);
#pragma unroll
    for (int s = 0; s < 4; ++s) gload_lds16(Bg[s] + k0, Bl[s]);
    __syncthreads();
#pragma unroll
    for (int h = 0; h < 2; ++h) {
      short8 af[2], bfr[4];
      int cc = quad + 4 * h;
#pragma unroll
      for (int i = 0; i < 2; ++i) {
        int r = wm + i * 16 + lr;
        af[i] = *(const short8*)(&As[(r * 8 + (cc ^ (r & 7))) * 8]);
      }
#pragma unroll
      for (int j = 0; j < 4; ++j) {
        int r = wn + j * 16 + lr;
        bfr[j] = *(const short8*)(&Bs[(r * 8 + (cc ^ (r & 7))) * 8]);
      }
#pragma unroll
      for (int i = 0; i < 2; ++i)
#pragma unroll
        for (int j = 0; j < 4; ++j)
          acc[i][j] = __builtin_amdgcn_mfma_f32_16x16x32_bf16(af[i], bfr[j], acc[i][j], 0, 0, 0);
    }
  }

  int row0 = i64 * 64 + wm + quad * 4;
  int col0 = bn * 128 + wn + lr;
#pragma unroll
  for (int i = 0; i < 2; ++i) {
#pragma unroll
    for (int r = 0; r < 4; ++r) {
      int row = row0 + i * 16 + r;
      float s = 0.0f;
#pragma unroll
      for (int j = 0; j < 4; ++j) {
        int col = col0 + j * 16;
        float v = (col <= row) ? __expf(acc[i][j][r] * scale) : 0.0f;
        Sb[(size_t)row * ldc + col] = f2bf(v);
        s += v;
      }
#pragma unroll
      for (int o = 8; o > 0; o >>= 1) s += __shfl_xor(s, o, 64);
      if (lr == 0) unsafeAtomicAdd(&lvec[row], s);
    }
  }
}

// ---------------- O-gemm: 128x128, triangular K-chunks, XCD-swizzled --------
__global__ __launch_bounds__(256) void gemm_o(
    const uint16_t* __restrict__ Sb, const uint16_t* __restrict__ Vt,
    float* __restrict__ Opart)
{
  constexpr int BK = 64;
  __shared__ uint16_t As[128 * BK];
  __shared__ uint16_t Bs[128 * BK];
  int id = blockIdx.x;
  int bn = id / 80, p = id % 80;
  int c, bm;
  if      (p < 32) { c = 0; bm = p; }
  else if (p < 56) { c = 1; bm = p - 24; }
  else if (p < 72) { c = 2; bm = p - 40; }
  else             { c = 3; bm = p - 48; }
  int klo = c << 10;
  int khi = (bm + 1) << 7; if (khi > ((c + 1) << 10)) khi = (c + 1) << 10;

  int tid  = threadIdx.x;
  int lane = tid & 63;
  int wave = tid >> 6;
  int wm = (wave >> 1) * 64, wn = (wave & 1) * 64;
  int lr = lane & 15, quad = lane >> 4;

  const uint16_t *Ag[4], *Bg[4];
  uint16_t *Al[4], *Bl[4];
#pragma unroll
  for (int s = 0; s < 4; ++s) {
    int cch = tid + 256 * s;
    int r = cch >> 3, q = (cch & 7) ^ (r & 7);
    Ag[s] = Sb + (size_t)(bm * 128 + r) * 4096 + q * 8;
    Bg[s] = Vt + (size_t)(bn * 128 + r) * 4096 + q * 8;
    Al[s] = As + cch * 8;
    Bl[s] = Bs + cch * 8;
  }

  f32x4 acc[4][4] = {};

  for (int k0 = klo; k0 < khi; k0 += BK) {
    __syncthreads();
#pragma unroll
    for (int s = 0; s < 4; ++s) gload_lds16(Ag[s] + k0, Al[s]);
#pragma unroll
    for (int s = 0; s < 4; ++s) gload_lds16(Bg[s] + k0, Bl[s]);
    __syncthreads();
#pragma unroll
    for (int h = 0; h < 2; ++h) {
      short8 af[4], bfr[4];
      int cc = quad + 4 * h;
#pragma unroll
      for (int i = 0; i < 4; ++i) {
        int r = wm + i * 16 + lr;
        af[i] = *(const short8*)(&As[(r * 8 + (cc ^ (r & 7))) * 8]);
      }
#pragma unroll
      for (int j = 0; j < 4; ++j) {
        int r = wn + j * 16 + lr;
        bfr[j] = *(const short8*)(&Bs[(r * 8 + (cc ^ (r & 7))) * 8]);
      }
#pragma unroll
      for (int i = 0; i < 4; ++i)
#pragma unroll
        for (int j = 0; j < 4; ++j)
          acc[i][j] = __builtin_amdgcn_mfma_f32_16x16x32_bf16(af[i], bfr[j], acc[i][j], 0, 0, 0);
    }
  }

  float* P = Opart + (size_t)c * 4194304;
  int row0 = bm * 128 + wm + quad * 4;
  int col0 = bn * 128 + wn + lr;
#pragma unroll
  for (int j = 0; j < 4; ++j)
#pragma unroll
    for (int i = 0; i < 4; ++i)
#pragma unroll
      for (int r = 0; r < 4; ++r)
        P[(size_t)(row0 + i * 16 + r) * 1024 + col0 + j * 16] = acc[i][j][r];
}

// ---------------- FFN2: 128x64, split-K=2, atomic epilogue, XCD-swizzled ----
__global__ __launch_bounds__(256) void gemm_ffn2(
    const uint16_t* __restrict__ A, const uint16_t* __restrict__ Bt,
    float* __restrict__ Cout)
{
  constexpr int BK = 64;
  __shared__ uint16_t As[128 * BK];
  __shared__ uint16_t Bs[64 * BK];
  int id = blockIdx.x;
  int bn = id >> 6, p = id & 63;
  int bm = p >> 1, half = p & 1;
  int klo = half ? 2048 : 0, khi = half ? 4096 : 2048;

  int tid  = threadIdx.x;
  int lane = tid & 63;
  int wave = tid >> 6;
  int wm = (wave & 1) * 64, wn = (wave >> 1) * 32;
  int lr = lane & 15, quad = lane >> 4;

  const uint16_t *Ag[4], *Bg[2];
  uint16_t *Al[4], *Bl[2];
#pragma unroll
  for (int s = 0; s < 4; ++s) {
    int c = tid + 256 * s;
    int r = c >> 3, q = (c & 7) ^ (r & 7);
    Ag[s] = A + (size_t)(bm * 128 + r) * 4096 + q * 8;
    Al[s] = As + c * 8;
  }
#pragma unroll
  for (int s = 0; s < 2; ++s) {
    int c = tid + 256 * s;
    int r = c >> 3, q = (c & 7) ^ (r & 7);
    Bg[s] = Bt + (size_t)(bn * 64 + r) * 4096 + q * 8;
    Bl[s] = Bs + c * 8;
  }

  f32x4 acc[4][2] = {};

  for (int k0 = klo; k0 < khi; k0 += BK) {
    __syncthreads();
#pragma unroll
    for (int s = 0; s < 4; ++s) gload_lds16(Ag[s] + k0, Al[s]);
#pragma unroll
    for (int s = 0; s < 2; ++s) gload_lds16(Bg[s] + k0, Bl[s]);
    __syncthreads();
#pragma unroll
    for (int h = 0; h < 2; ++h) {
      short8 af[4], bfr[2];
      int cc = quad + 4 * h;
#pragma unroll
      for (int i = 0; i < 4; ++i) {
        int r = wm + i * 16 + lr;
        af[i] = *(const short8*)(&As[(r * 8 + (cc ^ (r & 7))) * 8]);
      }
#pragma unroll
      for (int j = 0; j < 2; ++j) {
        int r = wn + j * 16 + lr;
        bfr[j] = *(const short8*)(&Bs[(r * 8 + (cc ^ (r & 7))) * 8]);
      }
#pragma unroll
      for (int i = 0; i < 4; ++i)
#pragma unroll
        for (int j = 0; j < 2; ++j)
          acc[i][j] = __builtin_amdgcn_mfma_f32_16x16x32_bf16(af[i], bfr[j], acc[i][j], 0, 0, 0);
    }
  }

  int row0 = bm * 128 + wm + quad * 4;
  int col0 = bn * 64 + wn + lr;
#pragma unroll
  for (int j = 0; j < 2; ++j)
#pragma unroll
    for (int i = 0; i < 4; ++i)
#pragma unroll
      for (int r = 0; r < 4; ++r) {
        size_t idx = (size_t)(row0 + i * 16 + r) * 1024 + col0 + j * 16;
        unsafeAtomicAdd(&Cout[idx], acc[i][j][r]);
      }
}

// ---------------- reductions ------------------------------------------------
__device__ __forceinline__ float block_sum(float v, float* red) {
#pragma unroll
  for (int o = 32; o > 0; o >>= 1) v += __shfl_xor(v, o, 64);
  if ((threadIdx.x & 63) == 0) red[threadIdx.x >> 6] = v;
  __syncthreads();
  v = red[0] + red[1] + red[2] + red[3];
  __syncthreads();
  return v;
}

// ------ O-chunk-partials reduce /l + residual + LayerNorm -> bf16 -----------
__global__ __launch_bounds__(256) void add_layernorm(
    const float* __restrict__ P, const float* __restrict__ l,
    const float* __restrict__ emb, const float* __restrict__ gamma,
    const float* __restrict__ beta, uint16_t* __restrict__ xB)
{
  __shared__ float red[4];
  int i = blockIdx.x, tid = threadIdx.x;
  float inv_l = 1.0f / l[i];
  int nc = (i >> 10) + 1;
  float s0 = 0.0f, s1 = 0.0f, s2 = 0.0f, s3 = 0.0f;
  for (int c = 0; c < nc; ++c) {
    float4 a = ((const float4*)(P + (size_t)c * 4194304 + (size_t)i * 1024))[tid];
    s0 += a.x; s1 += a.y; s2 += a.z; s3 += a.w;
  }
  float4 b = ((const float4*)(emb + (size_t)i * 1024))[tid];
  float x0 = s0 * inv_l + b.x, x1 = s1 * inv_l + b.y;
  float x2 = s2 * inv_l + b.z, x3 = s3 * inv_l + b.w;
  float mu = block_sum(x0 + x1 + x2 + x3, red) * (1.0f / 1024.0f);
  float d0 = x0 - mu, d1 = x1 - mu, d2 = x2 - mu, d3 = x3 - mu;
  float var = block_sum(d0 * d0 + d1 * d1 + d2 * d2 + d3 * d3, red) * (1.0f / 1024.0f);
  float rs = rsqrtf(var + 1e-5f);
  float4 g  = ((const float4*)gamma)[tid];
  float4 be = ((const float4*)beta)[tid];
  ushort4 o;
  o.x = f2bf(d0 * rs * g.x + be.x);
  o.y = f2bf(d1 * rs * g.y + be.y);
  o.z = f2bf(d2 * rs * g.z + be.z);
  o.w = f2bf(d3 * rs * g.w + be.w);
  ((ushort4*)(xB + (size_t)i * 1024))[tid] = o;
}

// ---------------- prep: all casts/transposes/bias/init in one launch --------
__global__ __launch_bounds__(256) void prep(
    const float* __restrict__ emb, const float* __restrict__ Wq,
    const float* __restrict__ Wk, const float* __restrict__ Wv,
    const float* __restrict__ W1, const float* __restrict__ W2,
    const float* __restrict__ bq, const float* __restrict__ bk,
    const float* __restrict__ bv, const float* __restrict__ b2,
    uint16_t* __restrict__ embB, uint16_t* __restrict__ WqkvT,
    uint16_t* __restrict__ W1T, uint16_t* __restrict__ W2T,
    float* __restrict__ bqkv, float* __restrict__ lvec,
    float* __restrict__ outInit)
{
  __shared__ float tile[32][33];
  int b = blockIdx.x, tid = threadIdx.x;
  if (b < 4096) {                        // emb cast
    int idx = b * 256 + tid;
    float4 v = ((const float4*)emb)[idx];
    ushort4 o; o.x = f2bf(v.x); o.y = f2bf(v.y); o.z = f2bf(v.z); o.w = f2bf(v.w);
    ((ushort4*)embB)[idx] = o;
    return;
  }
  int tx = tid & 31, ty = tid >> 5;
  if (b < 7168) {                        // Wq/Wk/Wv -> WqkvT
    int local = b - 4096;
    const float* in = (local < 1024) ? Wq : (local < 2048) ? Wk : Wv;
    uint16_t* o = WqkvT + (size_t)(local >> 10) * 1048576;
    int rem = local & 1023;
    int r0 = (rem >> 5) * 32, c0 = (rem & 31) * 32;
#pragma unroll
    for (int r = 0; r < 32; r += 8)
      tile[ty + r][tx] = in[(size_t)(r0 + ty + r) * 1024 + c0 + tx];
    __syncthreads();
#pragma unroll
    for (int r = 0; r < 32; r += 8)
      o[(size_t)(c0 + ty + r) * 1024 + r0 + tx] = f2bf(tile[tx][ty + r]);
    return;
  }
  if (b < 11264) {                       // W1 -> W1T
    int local = b - 7168;
    int c0 = (local & 127) * 32, r0 = (local >> 7) * 32;
#pragma unroll
    for (int r = 0; r < 32; r += 8)
      tile[ty + r][tx] = W1[(size_t)(r0 + ty + r) * 4096 + c0 + tx];
    __syncthreads();
#pragma unroll
    for (int r = 0; r < 32; r += 8)
      W1T[(size_t)(c0 + ty + r) * 1024 + r0 + tx] = f2bf(tile[tx][ty + r]);
    return;
  }
  if (b < 15360) {                       // W2 -> W2T
    int local = b - 11264;
    int c0 = (local & 31) * 32, r0 = (local >> 5) * 32;
#pragma unroll
    for (int r = 0; r < 32; r += 8)
      tile[ty + r][tx] = W2[(size_t)(r0 + ty + r) * 1024 + c0 + tx];
    __syncthreads();
#pragma unroll
    for (int r = 0; r < 32; r += 8)
      W2T[(size_t)(c0 + ty + r) * 4096 + r0 + tx] = f2bf(tile[tx][ty + r]);
    return;
  }
  if (b < 15372) {                       // pack bq|bk|bv
    int i = (b - 15360) * 256 + tid;
    bqkv[i] = (i < 1024) ? bq[i] : (i < 2048) ? bk[i - 1024] : bv[i - 2048];
    return;
  }
  if (b == 15372) {                      // lvec = 0
#pragma unroll
    for (int i = tid; i < 4096; i += 256) lvec[i] = 0.0f;
    return;
  }
  {                                      // d_out row init = b2
    int row = b - 15373;
    float4 bv4 = ((const float4*)b2)[tid];
    ((float4*)(outInit + (size_t)row * 1024))[tid] = bv4;
  }
}

// ---------------- launcher --------------------------------------------------
extern "C" void kernel_launch(void* const* d_in, const int* in_sizes, int n_in,
                              void* d_out, int out_size, void* d_ws, size_t ws_size,
                              hipStream_t stream) {
  const float* emb   = (const float*)d_in[0];
  const float* Wq    = (const float*)d_in[1];
  const float* bq    = (const float*)d_in[2];
  const float* Wk    = (const float*)d_in[3];
  const float* bk    = (const float*)d_in[4];
  const float* Wv    = (const float*)d_in[5];
  const float* bv    = (const float*)d_in[6];
  const float* gamma = (const float*)d_in[7];
  const float* beta  = (const float*)d_in[8];
  const float* W1    = (const float*)d_in[9];
  const float* b1    = (const float*)d_in[10];
  const float* W2    = (const float*)d_in[11];
  const float* b2    = (const float*)d_in[12];

  char* w = (char*)d_ws;
  const size_t MB = 1ull << 20;
  uint16_t* embB  = (uint16_t*)(w + 0 * MB);    // [4096,1024] bf16
  uint16_t* WqkvT = (uint16_t*)(w + 8 * MB);    // [3072,1024]
  uint16_t* W1T   = (uint16_t*)(w + 14 * MB);   // [4096,1024]
  uint16_t* W2T   = (uint16_t*)(w + 22 * MB);   // [1024,4096]
  float*    bqkv  = (float*)(w + 30 * MB);      // [3072]
  float*    lvec  = (float*)(w + 30 * MB + 65536); // [4096]
  uint16_t* QKVb  = (uint16_t*)(w + 31 * MB);   // [4096,3072] (V cols unused)
  uint16_t* Vt    = (uint16_t*)(w + 55 * MB);   // [1024,4096]
  uint16_t* Sb    = (uint16_t*)(w + 63 * MB);   // [4096,4096] bf16 exp(S)
  uint16_t* hB    = (uint16_t*)(w + 63 * MB);   // reuses Sb (dead after O)
  float*    Opart = (float*)(w + 95 * MB);      // [4][4096,1024] fp32 chunks
  uint16_t* xB    = (uint16_t*)(w + 0 * MB);    // reuses embB
  // total ws requirement: 159 MB

  prep<<<19469, 256, 0, stream>>>(emb, Wq, Wk, Wv, W1, W2, bq, bk, bv, b2,
                                  embB, WqkvT, W1T, W2T, bqkv, lvec,
                                  (float*)d_out);

  // fused QKV: Q,K -> QKVb; V -> Vt via operand-swapped MFMA (no transpose)
  gemm_qkv<<<768, 256, 0, stream>>>(embB, WqkvT, bqkv, QKVb, Vt);
  const uint16_t* Qb = QKVb;
  const uint16_t* Kb = QKVb + 1024;

  // exp(S) = exp(QK^T/sqrt(D)), 64x128 causal tiles + fused row-sum atomics
  gemm_s<<<1056, 256, 0, stream>>>(Qb, Kb, Sb, lvec, 3072, 3072, 4096, 0.03125f);

  // O' = exp(S) @ V: 128x128 triangular K-chunks, XCD-swizzled, 640 blocks
  gemm_o<<<640, 256, 0, stream>>>(Sb, Vt, Opart);

  // reduce O chunk-partials, /l, + residual, LayerNorm -> xB
  add_layernorm<<<4096, 256, 0, stream>>>(Opart, lvec, emb, gamma, beta, xB);

  // FFN1 (XCD-swizzled 1-D grid)
  gemm_ffn1<<<1024, 256, 0, stream>>>(xB, W1T, b1, hB);

  // FFN2: XCD-swizzled split-K=2, atomicAdd into b2-initialized d_out
  gemm_ffn2<<<1024, 256, 0, stream>>>(hB, W2T, (float*)d_out);
}